// Round 1
// baseline (551.531 us; speedup 1.0000x reference)
//
#include <hip/hip_runtime.h>
#include <hip/hip_bf16.h>

// Problem constants (from setup_inputs): B=32, H=W=28, C=Co=192, T=1+784=785, heads=3, d=64
#define B_   32
#define Hh   28
#define Ww   28
#define Cc   192
#define T_   785
#define BT_  (B_ * T_)          // 25120
#define HEADS 3
#define Dd   64
#define SCALE 0.07216878364870323f   // 192^-0.5 (reference uses Co^-0.5)

// ---------------------------------------------------------------------------
// Kernel 1: depthwise 3x3 conv (SAME) + BN for one branch; cls token copied.
// grid (28, 32), block 192 (= C). Sliding window in registers, 3 loads/output.
// ---------------------------------------------------------------------------
__global__ __launch_bounds__(192) void conv_bn_k(
    const float* __restrict__ x, const float* __restrict__ cw,
    const float* __restrict__ g, const float* __restrict__ bb,
    const float* __restrict__ mu, const float* __restrict__ var,
    float* __restrict__ y)
{
  const int c = threadIdx.x;     // channel
  const int h = blockIdx.x;      // output row
  const int b = blockIdx.y;      // batch
  const float sc = g[c] * rsqrtf(var[c] + 1e-5f);
  const float sh = bb[c] - mu[c] * sc;
  float w9[9];
#pragma unroll
  for (int k = 0; k < 9; ++k) w9[k] = cw[c * 9 + k];
  const float* xb = x + (size_t)b * T_ * Cc;
  if (h == 0) y[(size_t)b * T_ * Cc + c] = xb[c];   // cls passthrough
  float c0[3], c1[3], c2[3];
#pragma unroll
  for (int r = 0; r < 3; ++r) {
    int rr = h - 1 + r;
    c0[r] = 0.f;
    c1[r] = (rr >= 0 && rr < Hh) ? xb[(size_t)(1 + rr * Ww) * Cc + c] : 0.f;
  }
  for (int col = 0; col < Ww; ++col) {
#pragma unroll
    for (int r = 0; r < 3; ++r) {
      int rr = h - 1 + r, c2i = col + 1;
      c2[r] = (rr >= 0 && rr < Hh && c2i < Ww)
                ? xb[(size_t)(1 + rr * Ww + c2i) * Cc + c] : 0.f;
    }
    float acc = c0[0]*w9[0] + c1[0]*w9[1] + c2[0]*w9[2]
              + c0[1]*w9[3] + c1[1]*w9[4] + c2[1]*w9[5]
              + c0[2]*w9[6] + c1[2]*w9[7] + c2[2]*w9[8];
    y[(size_t)(b * T_ + 1 + h * Ww + col) * Cc + c] = acc * sc + sh;
#pragma unroll
    for (int r = 0; r < 3; ++r) { c0[r] = c1[r]; c1[r] = c2[r]; }
  }
}

// ---------------------------------------------------------------------------
// Kernel 2: C[m][n] = sum_k A[m][k] * Bw[n][k] (+ bias[n]).  M=BT, N=K=192.
// 128x64 tile, BK=16, 256 threads, 8x4 per-thread. LDS staged transposed so
// inner-loop reads are float4 with <=2-way bank aliasing (free).
// ---------------------------------------------------------------------------
template <int BIAS>
__global__ __launch_bounds__(256) void gemm192(
    const float* __restrict__ A, const float* __restrict__ Bw,
    const float* __restrict__ bias, float* __restrict__ Cout)
{
  __shared__ float As[16][132];   // [k][m], pad 4
  __shared__ float Bs[16][68];    // [k][n], pad 4
  const int tid = threadIdx.x;
  const int m0 = blockIdx.x * 128;
  const int n0 = blockIdx.y * 64;
  const int ty = tid >> 4, tx = tid & 15;      // compute layout
  const int am = tid >> 1, akq = tid & 1;      // A staging: row, k-half
  const int bn = tid >> 2, bkq = tid & 3;      // B staging: row, k-quarter
  int arow = m0 + am; if (arow >= BT_) arow = BT_ - 1;   // clamp (stores guarded)
  const float* Ap = A + (size_t)arow * 192;
  const float* Bp = Bw + (size_t)(n0 + bn) * 192;
  float acc[8][4] = {};
  for (int k0 = 0; k0 < 192; k0 += 16) {
    float4 a0 = *(const float4*)(Ap + k0 + akq * 8);
    float4 a1 = *(const float4*)(Ap + k0 + akq * 8 + 4);
    float4 bv = *(const float4*)(Bp + k0 + bkq * 4);
    __syncthreads();
    As[akq*8+0][am] = a0.x; As[akq*8+1][am] = a0.y;
    As[akq*8+2][am] = a0.z; As[akq*8+3][am] = a0.w;
    As[akq*8+4][am] = a1.x; As[akq*8+5][am] = a1.y;
    As[akq*8+6][am] = a1.z; As[akq*8+7][am] = a1.w;
    Bs[bkq*4+0][bn] = bv.x; Bs[bkq*4+1][bn] = bv.y;
    Bs[bkq*4+2][bn] = bv.z; Bs[bkq*4+3][bn] = bv.w;
    __syncthreads();
#pragma unroll
    for (int kk = 0; kk < 16; ++kk) {
      float a_[8], b_[4];
      *(float4*)&a_[0] = *(const float4*)&As[kk][ty * 8];
      *(float4*)&a_[4] = *(const float4*)&As[kk][ty * 8 + 4];
      *(float4*)&b_[0] = *(const float4*)&Bs[kk][tx * 4];
#pragma unroll
      for (int i = 0; i < 8; ++i)
#pragma unroll
        for (int j = 0; j < 4; ++j)
          acc[i][j] = fmaf(a_[i], b_[j], acc[i][j]);
    }
  }
  float bv_[4] = {0.f, 0.f, 0.f, 0.f};
  if (BIAS) { *(float4*)bv_ = *(const float4*)(bias + n0 + tx * 4); }
#pragma unroll
  for (int i = 0; i < 8; ++i) {
    int m = m0 + ty * 8 + i;
    if (m < BT_) {
      float4 o;
      o.x = acc[i][0] + bv_[0]; o.y = acc[i][1] + bv_[1];
      o.z = acc[i][2] + bv_[2]; o.w = acc[i][3] + bv_[3];
      *(float4*)(Cout + (size_t)m * 192 + n0 + tx * 4) = o;
    }
  }
}

// ---------------------------------------------------------------------------
// Kernel 3: flash attention. grid (13 qtiles, 3 heads, 32 batch), 256 thr.
// Q/K in LDS d-major ([d][row]) -> S-GEMM reads are float4; V row-major;
// P row-major. Online softmax via 4-wide __shfl_xor within each 16-lane row
// group (all intra-wave). 64q x 64k tiles, 4x4 per-thread register blocks.
// ---------------------------------------------------------------------------
__global__ __launch_bounds__(256) void attn_k(
    const float* __restrict__ qkv, float* __restrict__ out)
{
  __shared__ float Qs[64][68];   // [d][r]
  __shared__ float Ks[64][68];   // [d][c]
  __shared__ float Vs[64][68];   // [c][d]
  __shared__ float Ps[64][68];   // [r][c]
  const int qt = blockIdx.x, hh = blockIdx.y, b = blockIdx.z;
  const int tid = threadIdx.x;
  const float* Q = qkv + ((size_t)(0 * B_ + b) * T_) * Cc + hh * Dd;
  const float* K = qkv + ((size_t)(1 * B_ + b) * T_) * Cc + hh * Dd;
  const float* V = qkv + ((size_t)(2 * B_ + b) * T_) * Cc + hh * Dd;
  const int t0 = qt * 64;
  const int sr = tid >> 2, sdq = tid & 3;    // staging: row, d-quarter
  {
    int tq = t0 + sr; if (tq >= T_) tq = T_ - 1;
    const float* qp = Q + (size_t)tq * Cc;
#pragma unroll
    for (int it = 0; it < 4; ++it) {
      int d0 = it * 16 + sdq * 4;
      float4 v = *(const float4*)(qp + d0);
      Qs[d0+0][sr] = v.x; Qs[d0+1][sr] = v.y;
      Qs[d0+2][sr] = v.z; Qs[d0+3][sr] = v.w;
    }
  }
  const int ry = tid >> 4, cx = tid & 15;
  float o[4][4] = {};
  float m_run[4] = {-1e30f, -1e30f, -1e30f, -1e30f};
  float l_run[4] = {0.f, 0.f, 0.f, 0.f};
  for (int kt = 0; kt < 13; ++kt) {
    __syncthreads();                       // prev PV done before restage
    {
      int tk = kt * 64 + sr; if (tk >= T_) tk = T_ - 1;
      const float* kp = K + (size_t)tk * Cc;
      const float* vp = V + (size_t)tk * Cc;
#pragma unroll
      for (int it = 0; it < 4; ++it) {
        int d0 = it * 16 + sdq * 4;
        float4 kv = *(const float4*)(kp + d0);
        Ks[d0+0][sr] = kv.x; Ks[d0+1][sr] = kv.y;
        Ks[d0+2][sr] = kv.z; Ks[d0+3][sr] = kv.w;
        float4 vv = *(const float4*)(vp + d0);
        *(float4*)&Vs[sr][d0] = vv;
      }
    }
    __syncthreads();
    // S = Q K^T for this tile
    float s[4][4] = {};
#pragma unroll 8
    for (int d = 0; d < 64; ++d) {
      float qa[4], kb[4];
      *(float4*)qa = *(const float4*)&Qs[d][ry * 4];
      *(float4*)kb = *(const float4*)&Ks[d][cx * 4];
#pragma unroll
      for (int i = 0; i < 4; ++i)
#pragma unroll
        for (int j = 0; j < 4; ++j)
          s[i][j] = fmaf(qa[i], kb[j], s[i][j]);
    }
    const int kbase = kt * 64 + cx * 4;
#pragma unroll
    for (int i = 0; i < 4; ++i) {
#pragma unroll
      for (int j = 0; j < 4; ++j)
        s[i][j] = (kbase + j < T_) ? s[i][j] * SCALE : -1e30f;
      float mr = fmaxf(fmaxf(s[i][0], s[i][1]), fmaxf(s[i][2], s[i][3]));
      mr = fmaxf(mr, __shfl_xor(mr, 1));
      mr = fmaxf(mr, __shfl_xor(mr, 2));
      mr = fmaxf(mr, __shfl_xor(mr, 4));
      mr = fmaxf(mr, __shfl_xor(mr, 8));
      float mnew = fmaxf(m_run[i], mr);
      float corr = __expf(m_run[i] - mnew);
      m_run[i] = mnew;
      float rs = 0.f;
#pragma unroll
      for (int j = 0; j < 4; ++j) {
        float p = __expf(s[i][j] - mnew);
        s[i][j] = p; rs += p;
      }
      rs += __shfl_xor(rs, 1); rs += __shfl_xor(rs, 2);
      rs += __shfl_xor(rs, 4); rs += __shfl_xor(rs, 8);
      l_run[i] = l_run[i] * corr + rs;
#pragma unroll
      for (int j = 0; j < 4; ++j) o[i][j] *= corr;
      *(float4*)&Ps[ry * 4 + i][cx * 4] = *(float4*)&s[i][0];
    }
    __syncthreads();
    // O += P V
#pragma unroll 8
    for (int c = 0; c < 64; ++c) {
      float vv[4], pa[4];
      *(float4*)vv = *(const float4*)&Vs[c][cx * 4];
#pragma unroll
      for (int i = 0; i < 4; ++i) pa[i] = Ps[ry * 4 + i][c];
#pragma unroll
      for (int i = 0; i < 4; ++i)
#pragma unroll
        for (int j = 0; j < 4; ++j)
          o[i][j] = fmaf(pa[i], vv[j], o[i][j]);
    }
  }
#pragma unroll
  for (int i = 0; i < 4; ++i) {
    int tq = t0 + ry * 4 + i;
    if (tq < T_) {
      float inv = 1.f / l_run[i];
      float4 ov;
      ov.x = o[i][0] * inv; ov.y = o[i][1] * inv;
      ov.z = o[i][2] * inv; ov.w = o[i][3] * inv;
      *(float4*)(out + ((size_t)b * T_ + tq) * Cc + hh * Dd + cx * 4) = ov;
    }
  }
}

// ---------------------------------------------------------------------------
extern "C" void kernel_launch(void* const* d_in, const int* in_sizes, int n_in,
                              void* d_out, int out_size, void* d_ws, size_t ws_size,
                              hipStream_t stream) {
  (void)in_sizes; (void)n_in; (void)out_size; (void)ws_size;
  const float* x        = (const float*)d_in[0];
  const float* conv_w   = (const float*)d_in[1];
  const float* bn_scale = (const float*)d_in[2];
  const float* bn_bias  = (const float*)d_in[3];
  const float* bn_mean  = (const float*)d_in[4];
  const float* bn_var   = (const float*)d_in[5];
  const float* w_qkv    = (const float*)d_in[6];
  const float* w_proj   = (const float*)d_in[7];
  const float* b_proj   = (const float*)d_in[8];

  float* qkv  = (float*)d_ws;                       // 3*B*T*C floats (57.9 MB)
  float* ytmp = qkv + (size_t)3 * B_ * T_ * Cc;     // B*T*C floats (19.3 MB)

  const int mblocks = (BT_ + 127) / 128;            // 197
  for (int i = 0; i < 3; ++i) {
    conv_bn_k<<<dim3(Hh, B_), 192, 0, stream>>>(
        x, conv_w + (size_t)i * Cc * 9,
        bn_scale + i * Cc, bn_bias + i * Cc, bn_mean + i * Cc, bn_var + i * Cc,
        ytmp);
    gemm192<0><<<dim3(mblocks, 3), 256, 0, stream>>>(
        ytmp, w_qkv + (size_t)i * Cc * Cc, nullptr, qkv + (size_t)i * B_ * T_ * Cc);
  }
  attn_k<<<dim3(13, HEADS, B_), 256, 0, stream>>>(qkv, ytmp);
  gemm192<1><<<dim3(mblocks, 3), 256, 0, stream>>>(
      ytmp, w_proj, b_proj, (float*)d_out);
}

// Round 2
// 186.694 us; speedup vs baseline: 2.9542x; 2.9542x over previous
//
#include <hip/hip_runtime.h>

#define B_   32
#define Hh   28
#define Ww   28
#define Cc   192
#define T_   785
#define BT_  (B_ * T_)          // 25120
#define BTC_ ((size_t)BT_ * Cc) // 4823040
#define SCALE 0.07216878364870323f   // 192^-0.5

typedef __attribute__((ext_vector_type(8))) __bf16 bf16x8;
typedef __attribute__((ext_vector_type(4))) __bf16 bf16x4;
typedef __attribute__((ext_vector_type(4))) float  f32x4;

__device__ __forceinline__ int imin(int a, int b) { return a < b ? a : b; }

// ---------------------------------------------------------------------------
// fp32 -> bf16 weight cast
// ---------------------------------------------------------------------------
__global__ void wcvt_k(const float* __restrict__ src, __bf16* __restrict__ dst, int n) {
  int i = blockIdx.x * 256 + threadIdx.x;
  if (i < n) dst[i] = (__bf16)src[i];
}

// ---------------------------------------------------------------------------
// Fused depthwise 3x3 conv + BN, ALL THREE branches, one read of x.
// grid (28, 32), block 192. Output bf16, y[branch][b*T+t][c].
// ---------------------------------------------------------------------------
__global__ __launch_bounds__(192) void conv3_bn_k(
    const float* __restrict__ x, const float* __restrict__ cw,
    const float* __restrict__ g, const float* __restrict__ bb,
    const float* __restrict__ mu, const float* __restrict__ var,
    __bf16* __restrict__ y)
{
  const int c = threadIdx.x;
  const int h = blockIdx.x;
  const int b = blockIdx.y;
  float w9[3][9], sc[3], sh[3];
#pragma unroll
  for (int br = 0; br < 3; ++br) {
    sc[br] = g[br * Cc + c] * rsqrtf(var[br * Cc + c] + 1e-5f);
    sh[br] = bb[br * Cc + c] - mu[br * Cc + c] * sc[br];
#pragma unroll
    for (int k = 0; k < 9; ++k) w9[br][k] = cw[(br * Cc + c) * 9 + k];
  }
  const float* xb = x + (size_t)b * T_ * Cc;
  if (h == 0) {
#pragma unroll
    for (int br = 0; br < 3; ++br)
      y[br * BTC_ + (size_t)b * T_ * Cc + c] = (__bf16)xb[c];   // cls passthrough
  }
  float c0[3], c1[3], c2[3];
#pragma unroll
  for (int r = 0; r < 3; ++r) {
    int rr = h - 1 + r;
    c0[r] = 0.f;
    c1[r] = (rr >= 0 && rr < Hh) ? xb[(size_t)(1 + rr * Ww) * Cc + c] : 0.f;
  }
  for (int col = 0; col < Ww; ++col) {
#pragma unroll
    for (int r = 0; r < 3; ++r) {
      int rr = h - 1 + r, ci = col + 1;
      c2[r] = (rr >= 0 && rr < Hh && ci < Ww)
                ? xb[(size_t)(1 + rr * Ww + ci) * Cc + c] : 0.f;
    }
    size_t orow = (size_t)(b * T_ + 1 + h * Ww + col) * Cc + c;
#pragma unroll
    for (int br = 0; br < 3; ++br) {
      float acc = c0[0]*w9[br][0] + c1[0]*w9[br][1] + c2[0]*w9[br][2]
                + c0[1]*w9[br][3] + c1[1]*w9[br][4] + c2[1]*w9[br][5]
                + c0[2]*w9[br][6] + c1[2]*w9[br][7] + c2[2]*w9[br][8];
      y[br * BTC_ + orow] = (__bf16)(acc * sc[br] + sh[br]);
    }
#pragma unroll
    for (int r = 0; r < 3; ++r) { c0[r] = c1[r]; c1[r] = c2[r]; }
  }
}

// ---------------------------------------------------------------------------
// MFMA GEMM: out[m][n] = sum_k A[m][k]*W[n][k] (+bias). M=25120, N=K=192.
// 128x64 block tile, 4 waves (2x2), each 64x32. BK=64 LDS chunks.
// A-frag: A[l&15 + mf*16 + wm*64][(l>>4)*8+j]; B-frag: W[l&15+...][(l>>4)*8+j].
// D-frag: row=(l>>4)*4+i, col=l&15.
// ---------------------------------------------------------------------------
template <int OUTF32>
__global__ __launch_bounds__(256) void gemm_bf16(
    const __bf16* __restrict__ A, const __bf16* __restrict__ Bw,
    const float* __restrict__ bias, void* __restrict__ outp, float oscale)
{
  __shared__ __bf16 As[128][72];   // 144B stride, 16B aligned
  __shared__ __bf16 Bs[64][72];
  const int tid = threadIdx.x;
  const int wid = tid >> 6, l = tid & 63, c = l & 15, g = l >> 4;
  const int wm = wid >> 1, wn = wid & 1;
  const int m0 = blockIdx.x * 128, n0 = blockIdx.y * 64;
  const int ar = tid >> 1, ah = tid & 1;     // A staging: row, k-half
  const int br2 = tid >> 2, bq = tid & 3;    // B staging: row, k-quarter

  f32x4 acc[4][2];
#pragma unroll
  for (int i = 0; i < 4; ++i)
#pragma unroll
    for (int j = 0; j < 2; ++j) acc[i][j] = (f32x4)(0.f);

  for (int kc = 0; kc < 3; ++kc) {
    const int k0 = kc * 64;
    const __bf16* ap = A + (size_t)imin(m0 + ar, BT_ - 1) * Cc + k0 + ah * 32;
    const __bf16* bp = Bw + (size_t)(n0 + br2) * Cc + k0 + bq * 16;
    uint4 a0 = *(const uint4*)(ap + 0);
    uint4 a1 = *(const uint4*)(ap + 8);
    uint4 a2 = *(const uint4*)(ap + 16);
    uint4 a3 = *(const uint4*)(ap + 24);
    uint4 b0 = *(const uint4*)(bp + 0);
    uint4 b1 = *(const uint4*)(bp + 8);
    __syncthreads();
    *(uint4*)&As[ar][ah * 32 + 0]  = a0;
    *(uint4*)&As[ar][ah * 32 + 8]  = a1;
    *(uint4*)&As[ar][ah * 32 + 16] = a2;
    *(uint4*)&As[ar][ah * 32 + 24] = a3;
    *(uint4*)&Bs[br2][bq * 16 + 0] = b0;
    *(uint4*)&Bs[br2][bq * 16 + 8] = b1;
    __syncthreads();
#pragma unroll
    for (int ksl = 0; ksl < 2; ++ksl) {
      bf16x8 af[4], bfr[2];
#pragma unroll
      for (int mf = 0; mf < 4; ++mf)
        af[mf] = *(const bf16x8*)&As[wm * 64 + mf * 16 + c][ksl * 32 + g * 8];
#pragma unroll
      for (int nf = 0; nf < 2; ++nf)
        bfr[nf] = *(const bf16x8*)&Bs[wn * 32 + nf * 16 + c][ksl * 32 + g * 8];
#pragma unroll
      for (int mf = 0; mf < 4; ++mf)
#pragma unroll
        for (int nf = 0; nf < 2; ++nf)
          acc[mf][nf] = __builtin_amdgcn_mfma_f32_16x16x32_bf16(
              af[mf], bfr[nf], acc[mf][nf], 0, 0, 0);
    }
  }
  float bias_c[2] = {0.f, 0.f};
  if (OUTF32) {
#pragma unroll
    for (int nf = 0; nf < 2; ++nf) bias_c[nf] = bias[n0 + wn * 32 + nf * 16 + c];
  }
#pragma unroll
  for (int mf = 0; mf < 4; ++mf) {
#pragma unroll
    for (int i = 0; i < 4; ++i) {
      int m = m0 + wm * 64 + mf * 16 + g * 4 + i;
      if (m < BT_) {
#pragma unroll
        for (int nf = 0; nf < 2; ++nf) {
          int n = n0 + wn * 32 + nf * 16 + c;
          if (OUTF32)
            ((float*)outp)[(size_t)m * Cc + n] = acc[mf][nf][i] + bias_c[nf];
          else
            ((__bf16*)outp)[(size_t)m * Cc + n] = (__bf16)(acc[mf][nf][i] * oscale);
        }
      }
    }
  }
}

// ---------------------------------------------------------------------------
// MFMA flash attention, swapped-operand scheme. grid (13, 3, 32), 4 waves.
// Wave w owns q-rows qt*64 + w*16 + (0..15). Per K-tile of 64 keys:
//   S^T = K_tile . Q^T  (A=K rows, B=Q rows, both b128 from LDS/regs)
//   per-lane softmax over 16 regs + shfl_xor(16,32)
//   P packed to per-wave LDS [qrow][key] (b64 writes, b128 reads)
//   O^T += V^T . P^T  (A=Vt from LDS, B=P)
// ---------------------------------------------------------------------------
__global__ __launch_bounds__(256) void attn_mfma(
    const __bf16* __restrict__ qkv, __bf16* __restrict__ aout)
{
  __shared__ __bf16 Ks[64][72];      // [key][d]
  __shared__ __bf16 Vt[64][72];      // [d][key]
  __shared__ __bf16 Ps[4][16][72];   // per-wave [qrow][key]
  const int tid = threadIdx.x;
  const int wid = tid >> 6, l = tid & 63, c = l & 15, g = l >> 4;
  const int qt = blockIdx.x, hh = blockIdx.y, b = blockIdx.z;
  const __bf16* Q = qkv + ((size_t)(0 * B_ + b) * T_) * Cc + hh * 64;
  const __bf16* K = qkv + ((size_t)(1 * B_ + b) * T_) * Cc + hh * 64;
  const __bf16* V = qkv + ((size_t)(2 * B_ + b) * T_) * Cc + hh * 64;

  // Q fragments held in registers for all 13 K-tiles (B-operand of S^T).
  const int qrow = qt * 64 + wid * 16 + c;
  const __bf16* qp = Q + (size_t)imin(qrow, T_ - 1) * Cc + g * 8;
  bf16x8 qf[2];
  qf[0] = *(const bf16x8*)(qp);
  qf[1] = *(const bf16x8*)(qp + 32);

  // staging ids
  const int skey = tid >> 2, sdq = tid & 3;        // K stage
  const int vkp = tid & 31, vd0 = (tid >> 5) * 8;  // Vt stage (key pair, d-octet)

  f32x4 ot[4];
#pragma unroll
  for (int f = 0; f < 4; ++f) ot[f] = (f32x4)(0.f);
  float m_run = -1e30f, l_run = 0.f;

  for (int kt = 0; kt < 13; ++kt) {
    __syncthreads();
    {
      // stage K rows (row-major)
      const __bf16* kp = K + (size_t)imin(kt * 64 + skey, T_ - 1) * Cc + sdq * 16;
      uint4 k0v = *(const uint4*)(kp + 0);
      uint4 k1v = *(const uint4*)(kp + 8);
      *(uint4*)&Ks[skey][sdq * 16 + 0] = k0v;
      *(uint4*)&Ks[skey][sdq * 16 + 8] = k1v;
      // stage V transposed: thread owns keys (2*vkp, 2*vkp+1), d = vd0..vd0+7
      const __bf16* v0 = V + (size_t)imin(kt * 64 + 2 * vkp + 0, T_ - 1) * Cc + vd0;
      const __bf16* v1 = V + (size_t)imin(kt * 64 + 2 * vkp + 1, T_ - 1) * Cc + vd0;
      uint4 va = *(const uint4*)v0;
      uint4 vb = *(const uint4*)v1;
      const ushort* pa = (const ushort*)&va;
      const ushort* pb = (const ushort*)&vb;
#pragma unroll
      for (int e = 0; e < 8; ++e) {
        unsigned pk = (unsigned)pa[e] | ((unsigned)pb[e] << 16);
        *(unsigned*)&Vt[vd0 + e][2 * vkp] = pk;
      }
    }
    __syncthreads();

    // S^T = K . Q^T : st[f] holds S^T[kt*64 + f*16 + g*4 + i][qrow(c)]
    f32x4 st[4];
#pragma unroll
    for (int f = 0; f < 4; ++f) st[f] = (f32x4)(0.f);
#pragma unroll
    for (int s = 0; s < 2; ++s) {
#pragma unroll
      for (int f = 0; f < 4; ++f) {
        bf16x8 ka = *(const bf16x8*)&Ks[f * 16 + c][s * 32 + g * 8];
        st[f] = __builtin_amdgcn_mfma_f32_16x16x32_bf16(ka, qf[s], st[f], 0, 0, 0);
      }
    }
    if (kt == 12) {   // mask keys >= 785 (local key index >= 17)
#pragma unroll
      for (int f = 0; f < 4; ++f)
#pragma unroll
        for (int i = 0; i < 4; ++i)
          if (f * 16 + g * 4 + i >= 17) st[f][i] = -1e30f;
    }
    // online softmax (per-lane over 16 values, then across groups)
    float pmax = -1e30f;
#pragma unroll
    for (int f = 0; f < 4; ++f)
#pragma unroll
      for (int i = 0; i < 4; ++i) pmax = fmaxf(pmax, st[f][i]);
    pmax = fmaxf(pmax, __shfl_xor(pmax, 16));
    pmax = fmaxf(pmax, __shfl_xor(pmax, 32));
    float mnew = fmaxf(m_run, pmax);
    float corr = __expf(m_run - mnew);
    m_run = mnew;
    float rs = 0.f;
#pragma unroll
    for (int f = 0; f < 4; ++f) {
      bf16x4 pk;
#pragma unroll
      for (int i = 0; i < 4; ++i) {
        float p = __expf(st[f][i] - mnew);
        rs += p;
        pk[i] = (__bf16)p;
      }
      *(bf16x4*)&Ps[wid][c][f * 16 + g * 4] = pk;   // packed b64 write
    }
    rs += __shfl_xor(rs, 16);
    rs += __shfl_xor(rs, 32);
    l_run = l_run * corr + rs;
#pragma unroll
    for (int f = 0; f < 4; ++f)
#pragma unroll
      for (int i = 0; i < 4; ++i) ot[f][i] *= corr;

    // O^T += V^T . P^T
#pragma unroll
    for (int s = 0; s < 2; ++s) {
      bf16x8 pb2 = *(const bf16x8*)&Ps[wid][c][s * 32 + g * 8];   // b128 read
#pragma unroll
      for (int f = 0; f < 4; ++f) {
        bf16x8 va2 = *(const bf16x8*)&Vt[f * 16 + c][s * 32 + g * 8];
        ot[f] = __builtin_amdgcn_mfma_f32_16x16x32_bf16(va2, pb2, ot[f], 0, 0, 0);
      }
    }
  }

  const int t = qt * 64 + wid * 16 + c;
  if (t < T_) {
    float inv = l_run > 0.f ? 1.f / l_run : 0.f;
    __bf16* op = aout + ((size_t)(b * T_ + t)) * Cc + hh * 64;
#pragma unroll
    for (int f = 0; f < 4; ++f) {
      bf16x4 ov;
#pragma unroll
      for (int i = 0; i < 4; ++i) ov[i] = (__bf16)(ot[f][i] * inv);
      *(bf16x4*)(op + f * 16 + g * 4) = ov;   // d = f*16+g*4+i
    }
  }
}

// ---------------------------------------------------------------------------
extern "C" void kernel_launch(void* const* d_in, const int* in_sizes, int n_in,
                              void* d_out, int out_size, void* d_ws, size_t ws_size,
                              hipStream_t stream) {
  (void)in_sizes; (void)n_in; (void)out_size; (void)ws_size;
  const float* x        = (const float*)d_in[0];
  const float* conv_w   = (const float*)d_in[1];
  const float* bn_scale = (const float*)d_in[2];
  const float* bn_bias  = (const float*)d_in[3];
  const float* bn_mean  = (const float*)d_in[4];
  const float* bn_var   = (const float*)d_in[5];
  const float* w_qkv    = (const float*)d_in[6];
  const float* w_proj   = (const float*)d_in[7];
  const float* b_proj   = (const float*)d_in[8];

  __bf16* ybf  = (__bf16*)d_ws;            // 3 * BTC (28.9 MB)
  __bf16* qkvb = ybf + 3 * BTC_;           // 3 * BTC (28.9 MB)
  __bf16* aobf = qkvb + 3 * BTC_;          // BTC (9.65 MB)
  __bf16* wq   = aobf + BTC_;              // 3*192*192
  __bf16* wp   = wq + 3 * Cc * Cc;         // 192*192

  wcvt_k<<<(3 * Cc * Cc + 255) / 256, 256, 0, stream>>>(w_qkv, wq, 3 * Cc * Cc);
  wcvt_k<<<(Cc * Cc + 255) / 256, 256, 0, stream>>>(w_proj, wp, Cc * Cc);
  conv3_bn_k<<<dim3(Hh, B_), 192, 0, stream>>>(
      x, conv_w, bn_scale, bn_bias, bn_mean, bn_var, ybf);

  const int mblocks = (BT_ + 127) / 128;   // 197
  for (int i = 0; i < 3; ++i) {
    gemm_bf16<0><<<dim3(mblocks, 3), 256, 0, stream>>>(
        ybf + (size_t)i * BTC_, wq + (size_t)i * Cc * Cc, nullptr,
        qkvb + (size_t)i * BTC_, i == 0 ? SCALE : 1.0f);
  }
  attn_mfma<<<dim3(13, 3, B_), 256, 0, stream>>>(qkvb, aobf);
  gemm_bf16<1><<<dim3(mblocks, 3), 256, 0, stream>>>(
      aobf, wp, b_proj, d_out, 1.0f);
}

// Round 3
// 181.652 us; speedup vs baseline: 3.0362x; 1.0278x over previous
//
#include <hip/hip_runtime.h>

#define B_   32
#define Hh   28
#define Ww   28
#define Cc   192
#define T_   785
#define BT_  (B_ * T_)          // 25120
#define BTC_ ((size_t)BT_ * Cc) // 4823040
// 192^-0.5 * log2(e): softmax computed in exp2 domain
#define SCALE2 0.10412163388f

typedef __attribute__((ext_vector_type(8))) __bf16 bf16x8;
typedef __attribute__((ext_vector_type(4))) __bf16 bf16x4;
typedef __attribute__((ext_vector_type(4))) float  f32x4;

__device__ __forceinline__ int imin(int a, int b) { return a < b ? a : b; }

// ---------------------------------------------------------------------------
// fp32 -> bf16 cast of both weight tensors in one launch.
// n = 4*192*192 = 147456 = 576*256 exactly.
// ---------------------------------------------------------------------------
__global__ void wcvt_k(const float* __restrict__ wq, const float* __restrict__ wp,
                       __bf16* __restrict__ dst) {
  int i = blockIdx.x * 256 + threadIdx.x;
  float v = (i < 3 * Cc * Cc) ? wq[i] : wp[i - 3 * Cc * Cc];
  dst[i] = (__bf16)v;
}

// ---------------------------------------------------------------------------
// Fused depthwise 3x3 conv + BN, all three branches, 2 output rows per block
// (cuts vertical halo re-reads of x: 3x -> 2x). grid (14, 32), block 192.
// ---------------------------------------------------------------------------
__global__ __launch_bounds__(192) void conv3_bn_k(
    const float* __restrict__ x, const float* __restrict__ cw,
    const float* __restrict__ g, const float* __restrict__ bb,
    const float* __restrict__ mu, const float* __restrict__ var,
    __bf16* __restrict__ y)
{
  const int c = threadIdx.x;
  const int h0 = blockIdx.x * 2;
  const int b = blockIdx.y;
  float w9[3][9], sc[3], sh[3];
#pragma unroll
  for (int br = 0; br < 3; ++br) {
    sc[br] = g[br * Cc + c] * rsqrtf(var[br * Cc + c] + 1e-5f);
    sh[br] = bb[br * Cc + c] - mu[br * Cc + c] * sc[br];
#pragma unroll
    for (int k = 0; k < 9; ++k) w9[br][k] = cw[(br * Cc + c) * 9 + k];
  }
  const float* xb = x + (size_t)b * T_ * Cc;
  if (h0 == 0) {
#pragma unroll
    for (int br = 0; br < 3; ++br)
      y[br * BTC_ + (size_t)b * T_ * Cc + c] = (__bf16)xb[c];   // cls passthrough
  }
  // window rows h0-1 .. h0+2 (4 rows), sliding 3-col window
  float c0[4], c1[4], c2[4];
#pragma unroll
  for (int r = 0; r < 4; ++r) {
    int rr = h0 - 1 + r;
    c0[r] = 0.f;
    c1[r] = (rr >= 0 && rr < Hh) ? xb[(size_t)(1 + rr * Ww) * Cc + c] : 0.f;
  }
  for (int col = 0; col < Ww; ++col) {
#pragma unroll
    for (int r = 0; r < 4; ++r) {
      int rr = h0 - 1 + r, ci = col + 1;
      c2[r] = (rr >= 0 && rr < Hh && ci < Ww)
                ? xb[(size_t)(1 + rr * Ww + ci) * Cc + c] : 0.f;
    }
#pragma unroll
    for (int ro = 0; ro < 2; ++ro) {
      size_t orow = (size_t)(b * T_ + 1 + (h0 + ro) * Ww + col) * Cc + c;
#pragma unroll
      for (int br = 0; br < 3; ++br) {
        float acc = c0[ro+0]*w9[br][0] + c1[ro+0]*w9[br][1] + c2[ro+0]*w9[br][2]
                  + c0[ro+1]*w9[br][3] + c1[ro+1]*w9[br][4] + c2[ro+1]*w9[br][5]
                  + c0[ro+2]*w9[br][6] + c1[ro+2]*w9[br][7] + c2[ro+2]*w9[br][8];
        y[br * BTC_ + orow] = (__bf16)(acc * sc[br] + sh[br]);
      }
    }
#pragma unroll
    for (int r = 0; r < 4; ++r) { c0[r] = c1[r]; c1[r] = c2[r]; }
  }
}

// ---------------------------------------------------------------------------
// MFMA GEMM: out[m][n] = sum_k A[m][k]*W[n][k] (+bias). M=25120, N=K=192.
// MODE 0: QKV — blockIdx.z = branch, bf16 out, branch 0 scaled by SCALE2.
// MODE 1: proj — f32 out + bias.
// 128x64 tile, 4 waves (2x2), register-prefetched staging.
// ---------------------------------------------------------------------------
template <int MODE>
__global__ __launch_bounds__(256) void gemm_bf16(
    const __bf16* __restrict__ A0, const __bf16* __restrict__ W0,
    const float* __restrict__ bias, void* __restrict__ outp)
{
  __shared__ __bf16 As[128][72];
  __shared__ __bf16 Bs[64][72];
  const int z = blockIdx.z;
  const __bf16* A  = A0 + (MODE == 0 ? (size_t)z * BTC_ : 0);
  const __bf16* Bw = W0 + (MODE == 0 ? (size_t)z * Cc * Cc : 0);
  const float oscale = (MODE == 0 && z == 0) ? SCALE2 : 1.0f;
  const int tid = threadIdx.x;
  const int wid = tid >> 6, l = tid & 63, c = l & 15, g = l >> 4;
  const int wm = wid >> 1, wn = wid & 1;
  const int m0 = blockIdx.x * 128, n0 = blockIdx.y * 64;
  const int ar = tid >> 1, ah = tid & 1;
  const int br2 = tid >> 2, bq = tid & 3;

  f32x4 acc[4][2];
#pragma unroll
  for (int i = 0; i < 4; ++i)
#pragma unroll
    for (int j = 0; j < 2; ++j) acc[i][j] = (f32x4)(0.f);

  const __bf16* ap = A + (size_t)imin(m0 + ar, BT_ - 1) * Cc + ah * 32;
  const __bf16* bp = Bw + (size_t)(n0 + br2) * Cc + bq * 16;
  uint4 a0 = *(const uint4*)(ap + 0);
  uint4 a1 = *(const uint4*)(ap + 8);
  uint4 a2 = *(const uint4*)(ap + 16);
  uint4 a3 = *(const uint4*)(ap + 24);
  uint4 b0 = *(const uint4*)(bp + 0);
  uint4 b1 = *(const uint4*)(bp + 8);

  for (int kc = 0; kc < 3; ++kc) {
    __syncthreads();
    *(uint4*)&As[ar][ah * 32 + 0]  = a0;
    *(uint4*)&As[ar][ah * 32 + 8]  = a1;
    *(uint4*)&As[ar][ah * 32 + 16] = a2;
    *(uint4*)&As[ar][ah * 32 + 24] = a3;
    *(uint4*)&Bs[br2][bq * 16 + 0] = b0;
    *(uint4*)&Bs[br2][bq * 16 + 8] = b1;
    if (kc < 2) {           // prefetch next K-chunk; latency hides under MFMA
      ap += 64; bp += 64;
      a0 = *(const uint4*)(ap + 0);
      a1 = *(const uint4*)(ap + 8);
      a2 = *(const uint4*)(ap + 16);
      a3 = *(const uint4*)(ap + 24);
      b0 = *(const uint4*)(bp + 0);
      b1 = *(const uint4*)(bp + 8);
    }
    __syncthreads();
#pragma unroll
    for (int ksl = 0; ksl < 2; ++ksl) {
      bf16x8 af[4], bfr[2];
#pragma unroll
      for (int mf = 0; mf < 4; ++mf)
        af[mf] = *(const bf16x8*)&As[wm * 64 + mf * 16 + c][ksl * 32 + g * 8];
#pragma unroll
      for (int nf = 0; nf < 2; ++nf)
        bfr[nf] = *(const bf16x8*)&Bs[wn * 32 + nf * 16 + c][ksl * 32 + g * 8];
#pragma unroll
      for (int mf = 0; mf < 4; ++mf)
#pragma unroll
        for (int nf = 0; nf < 2; ++nf)
          acc[mf][nf] = __builtin_amdgcn_mfma_f32_16x16x32_bf16(
              af[mf], bfr[nf], acc[mf][nf], 0, 0, 0);
    }
  }
  float bias_c[2] = {0.f, 0.f};
  if (MODE == 1) {
#pragma unroll
    for (int nf = 0; nf < 2; ++nf) bias_c[nf] = bias[n0 + wn * 32 + nf * 16 + c];
  }
#pragma unroll
  for (int mf = 0; mf < 4; ++mf) {
#pragma unroll
    for (int i = 0; i < 4; ++i) {
      int m = m0 + wm * 64 + mf * 16 + g * 4 + i;
      if (m < BT_) {
#pragma unroll
        for (int nf = 0; nf < 2; ++nf) {
          int n = n0 + wn * 32 + nf * 16 + c;
          if (MODE == 1)
            ((float*)outp)[(size_t)m * Cc + n] = acc[mf][nf][i] + bias_c[nf];
          else
            ((__bf16*)outp)[z * BTC_ + (size_t)m * Cc + n] =
                (__bf16)(acc[mf][nf][i] * oscale);
        }
      }
    }
  }
}

// ---------------------------------------------------------------------------
// MFMA flash attention, swapped-operand, register-prefetched K/V staging,
// exp2-domain online softmax with defer-max, XCD-chunked block mapping.
// 1-D grid 1248 = 13 qtiles * 3 heads * 32 batch. 4 waves.
// ---------------------------------------------------------------------------
__global__ __launch_bounds__(256) void attn_mfma(
    const __bf16* __restrict__ qkv, __bf16* __restrict__ aout)
{
  __shared__ __bf16 Ks[64][72];      // [key][d]
  __shared__ __bf16 Vt[64][72];      // [d][key]
  __shared__ __bf16 Ps[4][16][72];   // per-wave [qrow][key]
  const int bid = blockIdx.x;
  // XCD chunking: consecutive bid round-robin XCDs; give each XCD a
  // contiguous chunk of 156 = 12 (b,h) groups x 13 qtiles -> K/V L2-resident.
  const int swz = (bid & 7) * 156 + (bid >> 3);
  const int qt = swz % 13;
  const int g2 = swz / 13;
  const int hh = g2 % 3;
  const int b  = g2 / 3;
  const int tid = threadIdx.x;
  const int wid = tid >> 6, l = tid & 63, c = l & 15, g = l >> 4;
  const __bf16* Q = qkv + ((size_t)(0 * B_ + b) * T_) * Cc + hh * 64;
  const __bf16* K = qkv + ((size_t)(1 * B_ + b) * T_) * Cc + hh * 64;
  const __bf16* V = qkv + ((size_t)(2 * B_ + b) * T_) * Cc + hh * 64;

  // Q fragments in registers for all 13 K-tiles (already SCALE2-scaled).
  const int qrow = qt * 64 + wid * 16 + c;
  const __bf16* qp = Q + (size_t)imin(qrow, T_ - 1) * Cc + g * 8;
  bf16x8 qf[2];
  qf[0] = *(const bf16x8*)(qp);
  qf[1] = *(const bf16x8*)(qp + 32);

  const int skey = tid >> 2, sdq = tid & 3;        // K stage ids
  const int vkp = tid & 31, vd0 = (tid >> 5) * 8;  // Vt stage ids

  uint4 kr0, kr1, va, vb;                          // prefetch registers
  auto loadKV = [&](int kt2) {
    const __bf16* kp = K + (size_t)imin(kt2 * 64 + skey, T_ - 1) * Cc + sdq * 16;
    kr0 = *(const uint4*)(kp + 0);
    kr1 = *(const uint4*)(kp + 8);
    const __bf16* v0 = V + (size_t)imin(kt2 * 64 + 2 * vkp + 0, T_ - 1) * Cc + vd0;
    const __bf16* v1 = V + (size_t)imin(kt2 * 64 + 2 * vkp + 1, T_ - 1) * Cc + vd0;
    va = *(const uint4*)v0;
    vb = *(const uint4*)v1;
  };
  loadKV(0);

  f32x4 ot[4];
#pragma unroll
  for (int f = 0; f < 4; ++f) ot[f] = (f32x4)(0.f);
  float m_run = -1e30f, l_run = 0.f;

  for (int kt = 0; kt < 13; ++kt) {
    __syncthreads();                   // prev compute done reading LDS
    // write staged registers -> LDS
    *(uint4*)&Ks[skey][sdq * 16 + 0] = kr0;
    *(uint4*)&Ks[skey][sdq * 16 + 8] = kr1;
    {
      const ushort* pa = (const ushort*)&va;
      const ushort* pb = (const ushort*)&vb;
#pragma unroll
      for (int e = 0; e < 8; ++e) {
        unsigned pk2 = (unsigned)pa[e] | ((unsigned)pb[e] << 16);
        *(unsigned*)&Vt[vd0 + e][2 * vkp] = pk2;
      }
    }
    if (kt < 12) loadKV(kt + 1);       // latency spans compute below
    __syncthreads();

    // S^T = K . Q^T  (log2-domain scores; SCALE2 folded into Q)
    f32x4 st[4];
#pragma unroll
    for (int f = 0; f < 4; ++f) st[f] = (f32x4)(0.f);
#pragma unroll
    for (int s = 0; s < 2; ++s) {
#pragma unroll
      for (int f = 0; f < 4; ++f) {
        bf16x8 ka = *(const bf16x8*)&Ks[f * 16 + c][s * 32 + g * 8];
        st[f] = __builtin_amdgcn_mfma_f32_16x16x32_bf16(ka, qf[s], st[f], 0, 0, 0);
      }
    }
    if (kt == 12) {                    // mask keys >= 785 (local idx >= 17)
#pragma unroll
      for (int f = 0; f < 4; ++f)
#pragma unroll
        for (int i = 0; i < 4; ++i)
          if (f * 16 + g * 4 + i >= 17) st[f][i] = -1e30f;
    }
    // online softmax, exp2 domain, defer-max (skip rescale unless max grew >8)
    float pmax = -1e30f;
#pragma unroll
    for (int f = 0; f < 4; ++f)
#pragma unroll
      for (int i = 0; i < 4; ++i) pmax = fmaxf(pmax, st[f][i]);
    pmax = fmaxf(pmax, __shfl_xor(pmax, 16));
    pmax = fmaxf(pmax, __shfl_xor(pmax, 32));
    if (!__all(pmax <= m_run + 8.f)) {
      float mnew = fmaxf(m_run, pmax);
      float corr = exp2f(m_run - mnew);
      m_run = mnew;
      l_run *= corr;
#pragma unroll
      for (int f = 0; f < 4; ++f)
#pragma unroll
        for (int i = 0; i < 4; ++i) ot[f][i] *= corr;
    }
    float rs = 0.f;
#pragma unroll
    for (int f = 0; f < 4; ++f) {
      bf16x4 pk;
#pragma unroll
      for (int i = 0; i < 4; ++i) {
        float p = exp2f(st[f][i] - m_run);
        rs += p;
        pk[i] = (__bf16)p;
      }
      *(bf16x4*)&Ps[wid][c][f * 16 + g * 4] = pk;
    }
    rs += __shfl_xor(rs, 16);
    rs += __shfl_xor(rs, 32);
    l_run += rs;

    // O^T += V^T . P^T
#pragma unroll
    for (int s = 0; s < 2; ++s) {
      bf16x8 pb2 = *(const bf16x8*)&Ps[wid][c][s * 32 + g * 8];
#pragma unroll
      for (int f = 0; f < 4; ++f) {
        bf16x8 va2 = *(const bf16x8*)&Vt[f * 16 + c][s * 32 + g * 8];
        ot[f] = __builtin_amdgcn_mfma_f32_16x16x32_bf16(va2, pb2, ot[f], 0, 0, 0);
      }
    }
  }

  const int t = qt * 64 + wid * 16 + c;
  if (t < T_) {
    float inv = 1.f / l_run;
    __bf16* op = aout + ((size_t)(b * T_ + t)) * Cc + hh * 64;
#pragma unroll
    for (int f = 0; f < 4; ++f) {
      bf16x4 ov;
#pragma unroll
      for (int i = 0; i < 4; ++i) ov[i] = (__bf16)(ot[f][i] * inv);
      *(bf16x4*)(op + f * 16 + g * 4) = ov;
    }
  }
}

// ---------------------------------------------------------------------------
extern "C" void kernel_launch(void* const* d_in, const int* in_sizes, int n_in,
                              void* d_out, int out_size, void* d_ws, size_t ws_size,
                              hipStream_t stream) {
  (void)in_sizes; (void)n_in; (void)out_size; (void)ws_size;
  const float* x        = (const float*)d_in[0];
  const float* conv_w   = (const float*)d_in[1];
  const float* bn_scale = (const float*)d_in[2];
  const float* bn_bias  = (const float*)d_in[3];
  const float* bn_mean  = (const float*)d_in[4];
  const float* bn_var   = (const float*)d_in[5];
  const float* w_qkv    = (const float*)d_in[6];
  const float* w_proj   = (const float*)d_in[7];
  const float* b_proj   = (const float*)d_in[8];

  __bf16* ybf  = (__bf16*)d_ws;            // 3 * BTC
  __bf16* qkvb = ybf + 3 * BTC_;           // 3 * BTC
  __bf16* aobf = qkvb + 3 * BTC_;          // BTC
  __bf16* wq   = aobf + BTC_;              // 3*192*192 (then 192*192 proj)
  __bf16* wp   = wq + 3 * Cc * Cc;

  wcvt_k<<<576, 256, 0, stream>>>(w_qkv, w_proj, wq);
  conv3_bn_k<<<dim3(14, B_), 192, 0, stream>>>(
      x, conv_w, bn_scale, bn_bias, bn_mean, bn_var, ybf);

  const int mblocks = (BT_ + 127) / 128;   // 197
  gemm_bf16<0><<<dim3(mblocks, 3, 3), 256, 0, stream>>>(ybf, wq, nullptr, qkvb);
  attn_mfma<<<1248, 256, 0, stream>>>(qkvb, aobf);
  gemm_bf16<1><<<dim3(mblocks, 3, 1), 256, 0, stream>>>(aobf, wp, b_proj, d_out);
}

// Round 4
// 179.424 us; speedup vs baseline: 3.0739x; 1.0124x over previous
//
#include <hip/hip_runtime.h>

#define B_   32
#define Hh   28
#define Ww   28
#define Cc   192
#define T_   785
#define BT_  (B_ * T_)          // 25120
#define BTC_ ((size_t)BT_ * Cc) // 4823040
// 192^-0.5 * log2(e): softmax computed in exp2 domain
#define SCALE2 0.10412163388f

typedef __attribute__((ext_vector_type(8))) __bf16 bf16x8;
typedef __attribute__((ext_vector_type(4))) __bf16 bf16x4;
typedef __attribute__((ext_vector_type(4))) float  f32x4;

// ---------------------------------------------------------------------------
// Fused depthwise 3x3 conv + BN (all 3 branches) + weight-cast side job.
// grid (29, 32), block 192. Rows 0..27: conv for one output row. Row 28:
// fp32->bf16 cast of w_qkv & w_proj (6144 threads x 24 elems = 147456).
// ---------------------------------------------------------------------------
__global__ __launch_bounds__(192) void conv3_bn_k(
    const float* __restrict__ x, const float* __restrict__ cw,
    const float* __restrict__ g, const float* __restrict__ bb,
    const float* __restrict__ mu, const float* __restrict__ var,
    __bf16* __restrict__ y,
    const float* __restrict__ wqkv, const float* __restrict__ wproj,
    __bf16* __restrict__ wdst)
{
  const int c = threadIdx.x;
  const int h = blockIdx.x;
  const int b = blockIdx.y;
  if (h == Hh) {                       // weight cast blocks
    int t = b * 192 + c;               // 0..6143
    int base = t * 24;
    const float* src = (base < 3 * Cc * Cc) ? (wqkv + base)
                                            : (wproj + (base - 3 * Cc * Cc));
#pragma unroll
    for (int e = 0; e < 24; e += 4) {
      float4 v = *(const float4*)(src + e);
      wdst[base + e + 0] = (__bf16)v.x;
      wdst[base + e + 1] = (__bf16)v.y;
      wdst[base + e + 2] = (__bf16)v.z;
      wdst[base + e + 3] = (__bf16)v.w;
    }
    return;
  }
  float w9[3][9], sc[3], sh[3];
#pragma unroll
  for (int br = 0; br < 3; ++br) {
    sc[br] = g[br * Cc + c] * rsqrtf(var[br * Cc + c] + 1e-5f);
    sh[br] = bb[br * Cc + c] - mu[br * Cc + c] * sc[br];
#pragma unroll
    for (int k = 0; k < 9; ++k) w9[br][k] = cw[(br * Cc + c) * 9 + k];
  }
  const float* xb = x + (size_t)b * T_ * Cc;
  if (h == 0) {
#pragma unroll
    for (int br = 0; br < 3; ++br)
      y[br * BTC_ + (size_t)b * T_ * Cc + c] = (__bf16)xb[c];   // cls passthrough
  }
  float c0[3], c1[3], c2[3];
#pragma unroll
  for (int r = 0; r < 3; ++r) {
    int rr = h - 1 + r;
    c0[r] = 0.f;
    c1[r] = (rr >= 0 && rr < Hh) ? xb[(size_t)(1 + rr * Ww) * Cc + c] : 0.f;
  }
  for (int col = 0; col < Ww; ++col) {
#pragma unroll
    for (int r = 0; r < 3; ++r) {
      int rr = h - 1 + r, ci = col + 1;
      c2[r] = (rr >= 0 && rr < Hh && ci < Ww)
                ? xb[(size_t)(1 + rr * Ww + ci) * Cc + c] : 0.f;
    }
    size_t orow = (size_t)(b * T_ + 1 + h * Ww + col) * Cc + c;
#pragma unroll
    for (int br = 0; br < 3; ++br) {
      float acc = c0[0]*w9[br][0] + c1[0]*w9[br][1] + c2[0]*w9[br][2]
                + c0[1]*w9[br][3] + c1[1]*w9[br][4] + c2[1]*w9[br][5]
                + c0[2]*w9[br][6] + c1[2]*w9[br][7] + c2[2]*w9[br][8];
      y[br * BTC_ + orow] = (__bf16)(acc * sc[br] + sh[br]);
    }
#pragma unroll
    for (int r = 0; r < 3; ++r) { c0[r] = c1[r]; c1[r] = c2[r]; }
  }
}

// ---------------------------------------------------------------------------
// MFMA GEMM, full-N tile: out[m][n] = sum_k A[m][k]*W[n][k] (+bias).
// Tile 128 x 192 (whole N) so A is read exactly once. 512 threads, 8 waves
// (2x4), each wave 64x48 (4x3 16-frags). K staged in 3 chunks of 64.
// MODE 0: QKV (blockIdx.z = branch, bf16 out, branch0 * SCALE2).
// MODE 1: proj (f32 out + bias).
// ---------------------------------------------------------------------------
template <int MODE>
__global__ __launch_bounds__(512) void gemm_bf16(
    const __bf16* __restrict__ A0, const __bf16* __restrict__ W0,
    const float* __restrict__ bias, void* __restrict__ outp)
{
  __shared__ __bf16 As[128][72];
  __shared__ __bf16 Bs[192][72];
  const int z = blockIdx.z;
  const __bf16* A  = A0 + (MODE == 0 ? (size_t)z * BTC_ : 0);
  const __bf16* Bw = W0 + (MODE == 0 ? (size_t)z * Cc * Cc : 0);
  const float osc = (MODE == 0 && z == 0) ? SCALE2 : 1.0f;
  const int tid = threadIdx.x;
  const int wid = tid >> 6, l = tid & 63, c = l & 15, g = l >> 4;
  const int wm = wid >> 2, wn = wid & 3;
  const int m0 = blockIdx.x * 128;
  // A staging: 4 threads/row, each 2 x b128
  const int ar = tid >> 2, aq = tid & 3;
  // B staging: 3 rows/thread (rows t>>3, 64+t>>3, 128+t>>3), vec v = t&7
  const int brow = tid >> 3, bv = tid & 7;

  f32x4 acc[4][3];
#pragma unroll
  for (int i = 0; i < 4; ++i)
#pragma unroll
    for (int j = 0; j < 3; ++j) acc[i][j] = (f32x4)(0.f);

  const __bf16* ap = A + (size_t)(m0 + ar) * Cc + aq * 16;   // OOB m reads spill into next ws buffer (mapped); stores guarded
  const __bf16* bp0 = Bw + (size_t)brow * Cc + bv * 8;
  uint4 a0 = *(const uint4*)(ap + 0);
  uint4 a1 = *(const uint4*)(ap + 8);
  uint4 b0 = *(const uint4*)(bp0 + 0 * 64 * Cc / 1);   // row brow
  uint4 b1 = *(const uint4*)(bp0 + (size_t)64 * Cc);   // row brow+64
  uint4 b2 = *(const uint4*)(bp0 + (size_t)128 * Cc);  // row brow+128

  for (int kc = 0; kc < 3; ++kc) {
    __syncthreads();
    *(uint4*)&As[ar][aq * 16 + 0] = a0;
    *(uint4*)&As[ar][aq * 16 + 8] = a1;
    *(uint4*)&Bs[brow +   0][bv * 8] = b0;
    *(uint4*)&Bs[brow +  64][bv * 8] = b1;
    *(uint4*)&Bs[brow + 128][bv * 8] = b2;
    if (kc < 2) {
      ap += 64; bp0 += 64;
      a0 = *(const uint4*)(ap + 0);
      a1 = *(const uint4*)(ap + 8);
      b0 = *(const uint4*)(bp0);
      b1 = *(const uint4*)(bp0 + (size_t)64 * Cc);
      b2 = *(const uint4*)(bp0 + (size_t)128 * Cc);
    }
    __syncthreads();
#pragma unroll
    for (int ksl = 0; ksl < 2; ++ksl) {
      bf16x8 af[4], bfr[3];
#pragma unroll
      for (int mf = 0; mf < 4; ++mf)
        af[mf] = *(const bf16x8*)&As[wm * 64 + mf * 16 + c][ksl * 32 + g * 8];
#pragma unroll
      for (int nf = 0; nf < 3; ++nf)
        bfr[nf] = *(const bf16x8*)&Bs[wn * 48 + nf * 16 + c][ksl * 32 + g * 8];
      __builtin_amdgcn_s_setprio(1);
#pragma unroll
      for (int mf = 0; mf < 4; ++mf)
#pragma unroll
        for (int nf = 0; nf < 3; ++nf)
          acc[mf][nf] = __builtin_amdgcn_mfma_f32_16x16x32_bf16(
              af[mf], bfr[nf], acc[mf][nf], 0, 0, 0);
      __builtin_amdgcn_s_setprio(0);
    }
  }
  float bias_c[3] = {0.f, 0.f, 0.f};
  if (MODE == 1) {
#pragma unroll
    for (int nf = 0; nf < 3; ++nf) bias_c[nf] = bias[wn * 48 + nf * 16 + c];
  }
#pragma unroll
  for (int mf = 0; mf < 4; ++mf) {
#pragma unroll
    for (int i = 0; i < 4; ++i) {
      int m = m0 + wm * 64 + mf * 16 + g * 4 + i;
      if (m < BT_) {
#pragma unroll
        for (int nf = 0; nf < 3; ++nf) {
          int n = wn * 48 + nf * 16 + c;
          if (MODE == 1)
            ((float*)outp)[(size_t)m * Cc + n] = acc[mf][nf][i] + bias_c[nf];
          else
            ((__bf16*)outp)[z * BTC_ + (size_t)m * Cc + n] =
                (__bf16)(acc[mf][nf][i] * osc);
        }
      }
    }
  }
}

// ---------------------------------------------------------------------------
// MFMA flash attention: 128 q-rows/block (2 fragment sets/wave), 4 waves.
// Swapped-operand S^T = K.Q^T; exp2-domain online softmax w/ defer-max;
// register-prefetched K/V staging; no clamps (OOB reads land in mapped ws,
// masked keys give P==0 so garbage V contributes nothing).
// grid 672 = 8 XCD chunks x 84 (12 (b,h) groups x 7 qtiles).
// ---------------------------------------------------------------------------
__global__ __launch_bounds__(256) void attn_mfma(
    const __bf16* __restrict__ qkv, __bf16* __restrict__ aout)
{
  __shared__ __bf16 Ks[64][72];      // [key][d]
  __shared__ __bf16 Vt[64][72];      // [d][key]
  __shared__ __bf16 Ps[4][16][72];   // per-wave [qrow][key]
  const int bid = blockIdx.x;
  const int swz = (bid & 7) * 84 + (bid >> 3);
  const int qt = swz % 7;
  const int g2 = swz / 7;
  const int hh = g2 % 3;
  const int b  = g2 / 3;
  const int tid = threadIdx.x;
  const int wid = tid >> 6, l = tid & 63, c = l & 15, g = l >> 4;
  const __bf16* Q = qkv + ((size_t)(0 * B_ + b) * T_) * Cc + hh * 64;
  const __bf16* K = qkv + ((size_t)(1 * B_ + b) * T_) * Cc + hh * 64;
  const __bf16* V = qkv + ((size_t)(2 * B_ + b) * T_) * Cc + hh * 64;

  // Two 16-row Q fragment sets per wave: rows q0+c and q0+16+c.
  const int q0 = qt * 128 + wid * 32;
  bf16x8 qf[2][2];
#pragma unroll
  for (int s = 0; s < 2; ++s) {
    const __bf16* qp = Q + (size_t)(q0 + s * 16 + c) * Cc + g * 8;
    qf[s][0] = *(const bf16x8*)(qp);
    qf[s][1] = *(const bf16x8*)(qp + 32);
  }

  const int skey = tid >> 2, sdq = tid & 3;        // K stage ids
  const int vkp = tid & 31, vd0 = (tid >> 5) * 8;  // Vt stage ids
  const __bf16* kp  = K + (size_t)skey * Cc + sdq * 16;
  const __bf16* vp0 = V + (size_t)(2 * vkp + 0) * Cc + vd0;
  const __bf16* vp1 = V + (size_t)(2 * vkp + 1) * Cc + vd0;
  uint4 kr0 = *(const uint4*)(kp + 0);
  uint4 kr1 = *(const uint4*)(kp + 8);
  uint4 va  = *(const uint4*)vp0;
  uint4 vb  = *(const uint4*)vp1;

  f32x4 ot[2][4];
#pragma unroll
  for (int s = 0; s < 2; ++s)
#pragma unroll
    for (int f = 0; f < 4; ++f) ot[s][f] = (f32x4)(0.f);
  float m_run[2] = {-1e30f, -1e30f};
  float l_run[2] = {0.f, 0.f};

  for (int kt = 0; kt < 13; ++kt) {
    __syncthreads();                   // prev tile's LDS reads done
    *(uint4*)&Ks[skey][sdq * 16 + 0] = kr0;
    *(uint4*)&Ks[skey][sdq * 16 + 8] = kr1;
    {
      const ushort* pa = (const ushort*)&va;
      const ushort* pb = (const ushort*)&vb;
#pragma unroll
      for (int e = 0; e < 8; ++e) {
        unsigned pk2 = (unsigned)pa[e] | ((unsigned)pb[e] << 16);
        *(unsigned*)&Vt[vd0 + e][2 * vkp] = pk2;
      }
    }
    if (kt < 12) {                     // prefetch next tile (hides under compute)
      kp += 64 * Cc; vp0 += 64 * Cc; vp1 += 64 * Cc;
      kr0 = *(const uint4*)(kp + 0);
      kr1 = *(const uint4*)(kp + 8);
      va  = *(const uint4*)vp0;
      vb  = *(const uint4*)vp1;
    }
    __syncthreads();

#pragma unroll
    for (int set = 0; set < 2; ++set) {
      // S^T = K . Q^T
      f32x4 st[4];
#pragma unroll
      for (int f = 0; f < 4; ++f) st[f] = (f32x4)(0.f);
      __builtin_amdgcn_s_setprio(1);
#pragma unroll
      for (int s2 = 0; s2 < 2; ++s2) {
#pragma unroll
        for (int f = 0; f < 4; ++f) {
          bf16x8 ka = *(const bf16x8*)&Ks[f * 16 + c][s2 * 32 + g * 8];
          st[f] = __builtin_amdgcn_mfma_f32_16x16x32_bf16(ka, qf[set][s2], st[f], 0, 0, 0);
        }
      }
      __builtin_amdgcn_s_setprio(0);
      if (kt == 12) {                  // mask keys >= 785 (local idx >= 17)
#pragma unroll
        for (int f = 0; f < 4; ++f)
#pragma unroll
          for (int i = 0; i < 4; ++i)
            if (f * 16 + g * 4 + i >= 17) st[f][i] = -1e30f;
      }
      // online softmax (exp2 domain, defer-max THR=8)
      float pmax = -1e30f;
#pragma unroll
      for (int f = 0; f < 4; ++f)
#pragma unroll
        for (int i = 0; i < 4; ++i) pmax = fmaxf(pmax, st[f][i]);
      pmax = fmaxf(pmax, __shfl_xor(pmax, 16));
      pmax = fmaxf(pmax, __shfl_xor(pmax, 32));
      if (!__all(pmax <= m_run[set] + 8.f)) {
        float mnew = fmaxf(m_run[set], pmax);
        float corr = exp2f(m_run[set] - mnew);
        m_run[set] = mnew;
        l_run[set] *= corr;
#pragma unroll
        for (int f = 0; f < 4; ++f)
#pragma unroll
          for (int i = 0; i < 4; ++i) ot[set][f][i] *= corr;
      }
      float rs = 0.f;
#pragma unroll
      for (int f = 0; f < 4; ++f) {
        bf16x4 pk;
#pragma unroll
        for (int i = 0; i < 4; ++i) {
          float p = exp2f(st[f][i] - m_run[set]);
          rs += p;
          pk[i] = (__bf16)p;
        }
        *(bf16x4*)&Ps[wid][c][f * 16 + g * 4] = pk;
      }
      rs += __shfl_xor(rs, 16);
      rs += __shfl_xor(rs, 32);
      l_run[set] += rs;

      // O^T += V^T . P^T
      __builtin_amdgcn_s_setprio(1);
#pragma unroll
      for (int s2 = 0; s2 < 2; ++s2) {
        bf16x8 pb2 = *(const bf16x8*)&Ps[wid][c][s2 * 32 + g * 8];
#pragma unroll
        for (int f = 0; f < 4; ++f) {
          bf16x8 va2 = *(const bf16x8*)&Vt[f * 16 + c][s2 * 32 + g * 8];
          ot[set][f] = __builtin_amdgcn_mfma_f32_16x16x32_bf16(va2, pb2, ot[set][f], 0, 0, 0);
        }
      }
      __builtin_amdgcn_s_setprio(0);
    }
  }

#pragma unroll
  for (int set = 0; set < 2; ++set) {
    const int t = q0 + set * 16 + c;
    if (t < T_) {
      float inv = 1.f / l_run[set];
      __bf16* op = aout + ((size_t)(b * T_ + t)) * Cc + hh * 64;
#pragma unroll
      for (int f = 0; f < 4; ++f) {
        bf16x4 ov;
#pragma unroll
        for (int i = 0; i < 4; ++i) ov[i] = (__bf16)(ot[set][f][i] * inv);
        *(bf16x4*)(op + f * 16 + g * 4) = ov;
      }
    }
  }
}

// ---------------------------------------------------------------------------
extern "C" void kernel_launch(void* const* d_in, const int* in_sizes, int n_in,
                              void* d_out, int out_size, void* d_ws, size_t ws_size,
                              hipStream_t stream) {
  (void)in_sizes; (void)n_in; (void)out_size; (void)ws_size;
  const float* x        = (const float*)d_in[0];
  const float* conv_w   = (const float*)d_in[1];
  const float* bn_scale = (const float*)d_in[2];
  const float* bn_bias  = (const float*)d_in[3];
  const float* bn_mean  = (const float*)d_in[4];
  const float* bn_var   = (const float*)d_in[5];
  const float* w_qkv    = (const float*)d_in[6];
  const float* w_proj   = (const float*)d_in[7];
  const float* b_proj   = (const float*)d_in[8];

  __bf16* ybf  = (__bf16*)d_ws;            // 3 * BTC
  __bf16* qkvb = ybf + 3 * BTC_;           // 3 * BTC (attn OOB reads spill into aobf: mapped)
  __bf16* aobf = qkvb + 3 * BTC_;          // BTC
  __bf16* wq   = aobf + BTC_;              // 3*192*192
  __bf16* wp   = wq + 3 * Cc * Cc;         // 192*192

  conv3_bn_k<<<dim3(Hh + 1, B_), 192, 0, stream>>>(
      x, conv_w, bn_scale, bn_bias, bn_mean, bn_var, ybf, w_qkv, w_proj, wq);

  const int mblocks = (BT_ + 127) / 128;   // 197
  gemm_bf16<0><<<dim3(mblocks, 1, 3), 512, 0, stream>>>(ybf, wq, nullptr, qkvb);
  attn_mfma<<<672, 256, 0, stream>>>(qkvb, aobf);
  gemm_bf16<1><<<dim3(mblocks, 1, 1), 512, 0, stream>>>(aobf, wp, b_proj, d_out);
}

// Round 7
// 177.032 us; speedup vs baseline: 3.1154x; 1.0135x over previous
//
#include <hip/hip_runtime.h>

#define B_   32
#define Hh   28
#define Ww   28
#define Cc   192
#define T_   785
#define BT_  (B_ * T_)          // 25120
#define BTC_ ((size_t)BT_ * Cc) // 4823040
// 192^-0.5 * log2(e): softmax computed in exp2 domain
#define SCALE2 0.10412163388f

typedef __attribute__((ext_vector_type(8))) __bf16 bf16x8;
typedef __attribute__((ext_vector_type(4))) __bf16 bf16x4;
typedef __attribute__((ext_vector_type(4))) float  f32x4;

// ---------------------------------------------------------------------------
// Fused depthwise 3x3 conv + BN (3 branches), 4 output rows per block
// (6 input rows -> 1.5x vertical re-read instead of 3x). grid (8, 32),
// block 192. bx==7 casts w_qkv/w_proj to bf16 (6144 thr x 24 elems).
// ---------------------------------------------------------------------------
__global__ __launch_bounds__(192) void conv3_bn_k(
    const float* __restrict__ x, const float* __restrict__ cw,
    const float* __restrict__ g, const float* __restrict__ bb,
    const float* __restrict__ mu, const float* __restrict__ var,
    __bf16* __restrict__ y,
    const float* __restrict__ wqkv, const float* __restrict__ wproj,
    __bf16* __restrict__ wdst)
{
  const int c = threadIdx.x;
  const int bx = blockIdx.x;
  const int b = blockIdx.y;
  if (bx == 7) {                       // weight cast blocks
    int t = b * 192 + c;               // 0..6143
    int base = t * 24;
    const float* src = (base < 3 * Cc * Cc) ? (wqkv + base)
                                            : (wproj + (base - 3 * Cc * Cc));
#pragma unroll
    for (int e = 0; e < 24; e += 4) {
      float4 v = *(const float4*)(src + e);
      wdst[base + e + 0] = (__bf16)v.x;
      wdst[base + e + 1] = (__bf16)v.y;
      wdst[base + e + 2] = (__bf16)v.z;
      wdst[base + e + 3] = (__bf16)v.w;
    }
    return;
  }
  const int h0 = bx * 4;
  float w9[3][9], sc[3], sh[3];
#pragma unroll
  for (int br = 0; br < 3; ++br) {
    sc[br] = g[br * Cc + c] * rsqrtf(var[br * Cc + c] + 1e-5f);
    sh[br] = bb[br * Cc + c] - mu[br * Cc + c] * sc[br];
#pragma unroll
    for (int k = 0; k < 9; ++k) w9[br][k] = cw[(br * Cc + c) * 9 + k];
  }
  const float* xb = x + (size_t)b * T_ * Cc;
  if (bx == 0) {
#pragma unroll
    for (int br = 0; br < 3; ++br)
      y[br * BTC_ + (size_t)b * T_ * Cc + c] = (__bf16)xb[c];   // cls passthrough
  }
  // sliding 3-col window over 6 input rows h0-1 .. h0+4
  float c0[6], c1[6], c2[6];
#pragma unroll
  for (int r = 0; r < 6; ++r) {
    int rr = h0 - 1 + r;
    c0[r] = 0.f;
    c1[r] = (rr >= 0 && rr < Hh) ? xb[(size_t)(1 + rr * Ww) * Cc + c] : 0.f;
  }
  for (int col = 0; col < Ww; ++col) {
#pragma unroll
    for (int r = 0; r < 6; ++r) {
      int rr = h0 - 1 + r, ci = col + 1;
      c2[r] = (rr >= 0 && rr < Hh && ci < Ww)
                ? xb[(size_t)(1 + rr * Ww + ci) * Cc + c] : 0.f;
    }
#pragma unroll
    for (int ro = 0; ro < 4; ++ro) {
      size_t orow = (size_t)(b * T_ + 1 + (h0 + ro) * Ww + col) * Cc + c;
#pragma unroll
      for (int br = 0; br < 3; ++br) {
        float acc = c0[ro+0]*w9[br][0] + c1[ro+0]*w9[br][1] + c2[ro+0]*w9[br][2]
                  + c0[ro+1]*w9[br][3] + c1[ro+1]*w9[br][4] + c2[ro+1]*w9[br][5]
                  + c0[ro+2]*w9[br][6] + c1[ro+2]*w9[br][7] + c2[ro+2]*w9[br][8];
        y[br * BTC_ + orow] = (__bf16)(acc * sc[br] + sh[br]);
      }
    }
#pragma unroll
    for (int r = 0; r < 6; ++r) { c0[r] = c1[r]; c1[r] = c2[r]; }
  }
}

// ---------------------------------------------------------------------------
// MFMA GEMM, full-N tile: out[m][n] = sum_k A[m][k]*W[n][k] (+bias).
// Tile 128 x 192 (whole N) so A is read exactly once. 512 threads, 8 waves
// (2x4), each wave 64x48. K staged in 3 chunks of 64, register-prefetched.
// MODE 0: QKV (blockIdx.z = branch, bf16 out, branch0 * SCALE2).
// MODE 1: proj (f32 out + bias).
// ---------------------------------------------------------------------------
template <int MODE>
__global__ __launch_bounds__(512) void gemm_bf16(
    const __bf16* __restrict__ A0, const __bf16* __restrict__ W0,
    const float* __restrict__ bias, void* __restrict__ outp)
{
  __shared__ __bf16 As[128][72];
  __shared__ __bf16 Bs[192][72];
  const int z = blockIdx.z;
  const __bf16* A  = A0 + (MODE == 0 ? (size_t)z * BTC_ : 0);
  const __bf16* Bw = W0 + (MODE == 0 ? (size_t)z * Cc * Cc : 0);
  const float osc = (MODE == 0 && z == 0) ? SCALE2 : 1.0f;
  const int tid = threadIdx.x;
  const int wid = tid >> 6, l = tid & 63, c = l & 15, g = l >> 4;
  const int wm = wid >> 2, wn = wid & 3;
  const int m0 = blockIdx.x * 128;
  const int ar = tid >> 2, aq = tid & 3;
  const int brow = tid >> 3, bv = tid & 7;

  f32x4 acc[4][3];
#pragma unroll
  for (int i = 0; i < 4; ++i)
#pragma unroll
    for (int j = 0; j < 3; ++j) acc[i][j] = (f32x4)(0.f);

  const __bf16* ap = A + (size_t)(m0 + ar) * Cc + aq * 16;   // OOB rows land in mapped ws; stores guarded
  const __bf16* bp0 = Bw + (size_t)brow * Cc + bv * 8;
  uint4 a0 = *(const uint4*)(ap + 0);
  uint4 a1 = *(const uint4*)(ap + 8);
  uint4 b0 = *(const uint4*)(bp0);
  uint4 b1 = *(const uint4*)(bp0 + (size_t)64 * Cc);
  uint4 b2 = *(const uint4*)(bp0 + (size_t)128 * Cc);

  for (int kc = 0; kc < 3; ++kc) {
    __syncthreads();
    *(uint4*)&As[ar][aq * 16 + 0] = a0;
    *(uint4*)&As[ar][aq * 16 + 8] = a1;
    *(uint4*)&Bs[brow +   0][bv * 8] = b0;
    *(uint4*)&Bs[brow +  64][bv * 8] = b1;
    *(uint4*)&Bs[brow + 128][bv * 8] = b2;
    if (kc < 2) {
      ap += 64; bp0 += 64;
      a0 = *(const uint4*)(ap + 0);
      a1 = *(const uint4*)(ap + 8);
      b0 = *(const uint4*)(bp0);
      b1 = *(const uint4*)(bp0 + (size_t)64 * Cc);
      b2 = *(const uint4*)(bp0 + (size_t)128 * Cc);
    }
    __syncthreads();
#pragma unroll
    for (int ksl = 0; ksl < 2; ++ksl) {
      bf16x8 af[4], bfr[3];
#pragma unroll
      for (int mf = 0; mf < 4; ++mf)
        af[mf] = *(const bf16x8*)&As[wm * 64 + mf * 16 + c][ksl * 32 + g * 8];
#pragma unroll
      for (int nf = 0; nf < 3; ++nf)
        bfr[nf] = *(const bf16x8*)&Bs[wn * 48 + nf * 16 + c][ksl * 32 + g * 8];
      __builtin_amdgcn_s_setprio(1);
#pragma unroll
      for (int mf = 0; mf < 4; ++mf)
#pragma unroll
        for (int nf = 0; nf < 3; ++nf)
          acc[mf][nf] = __builtin_amdgcn_mfma_f32_16x16x32_bf16(
              af[mf], bfr[nf], acc[mf][nf], 0, 0, 0);
      __builtin_amdgcn_s_setprio(0);
    }
  }
  float bias_c[3] = {0.f, 0.f, 0.f};
  if (MODE == 1) {
#pragma unroll
    for (int nf = 0; nf < 3; ++nf) bias_c[nf] = bias[wn * 48 + nf * 16 + c];
  }
#pragma unroll
  for (int mf = 0; mf < 4; ++mf) {
#pragma unroll
    for (int i = 0; i < 4; ++i) {
      int m = m0 + wm * 64 + mf * 16 + g * 4 + i;
      if (m < BT_) {
#pragma unroll
        for (int nf = 0; nf < 3; ++nf) {
          int n = wn * 48 + nf * 16 + c;
          if (MODE == 1)
            ((float*)outp)[(size_t)m * Cc + n] = acc[mf][nf][i] + bias_c[nf];
          else
            ((__bf16*)outp)[z * BTC_ + (size_t)m * Cc + n] =
                (__bf16)(acc[mf][nf][i] * osc);
        }
      }
    }
  }
}

// ---------------------------------------------------------------------------
// MFMA flash attention: 64 q-rows/block, 4 waves, DOUBLE-BUFFERED K/V LDS
// -> ONE barrier per K-tile. Swapped-operand S^T = K.Q^T; exp2-domain
// online softmax w/ defer-max; global loads for tile kt+2 issued before
// compute(kt). grid 1248 = 8 XCD chunks x 156.
// ---------------------------------------------------------------------------
__global__ __launch_bounds__(256) void attn_mfma(
    const __bf16* __restrict__ qkv, __bf16* __restrict__ aout)
{
  __shared__ __bf16 Ks[2][64][72];   // [buf][key][d]
  __shared__ __bf16 Vt[2][64][72];   // [buf][d][key]
  __shared__ __bf16 Ps[4][16][72];   // per-wave [qrow][key]
  const int bid = blockIdx.x;
  const int swz = (bid & 7) * 156 + (bid >> 3);
  const int qt = swz % 13;
  const int g2 = swz / 13;
  const int hh = g2 % 3;
  const int b  = g2 / 3;
  const int tid = threadIdx.x;
  const int wid = tid >> 6, l = tid & 63, c = l & 15, g = l >> 4;
  const __bf16* Q = qkv + ((size_t)(0 * B_ + b) * T_) * Cc + hh * 64;
  const __bf16* K = qkv + ((size_t)(1 * B_ + b) * T_) * Cc + hh * 64;
  const __bf16* V = qkv + ((size_t)(2 * B_ + b) * T_) * Cc + hh * 64;

  // Q fragments in registers for all 13 K-tiles (SCALE2 pre-folded).
  const int qrow = qt * 64 + wid * 16 + c;     // OOB rows read mapped ws; stores guarded
  const __bf16* qp = Q + (size_t)qrow * Cc + g * 8;
  bf16x8 qf0 = *(const bf16x8*)(qp);
  bf16x8 qf1 = *(const bf16x8*)(qp + 32);

  const int skey = tid >> 2, sdq = tid & 3;        // K stage ids
  const int vkp = tid & 31, vd0 = (tid >> 5) * 8;  // Vt stage ids
  const __bf16* kp  = K + (size_t)skey * Cc + sdq * 16;
  const __bf16* vp0 = V + (size_t)(2 * vkp + 0) * Cc + vd0;
  const __bf16* vp1 = V + (size_t)(2 * vkp + 1) * Cc + vd0;

  uint4 kr0, kr1, va, vb;
  auto loadKV = [&]() {
    kr0 = *(const uint4*)(kp + 0);
    kr1 = *(const uint4*)(kp + 8);
    va  = *(const uint4*)vp0;
    vb  = *(const uint4*)vp1;
    kp += 64 * Cc; vp0 += 64 * Cc; vp1 += 64 * Cc;
  };
  auto writeLDS = [&](int buf) {
    *(uint4*)&Ks[buf][skey][sdq * 16 + 0] = kr0;
    *(uint4*)&Ks[buf][skey][sdq * 16 + 8] = kr1;
    const ushort* pa = (const ushort*)&va;
    const ushort* pb = (const ushort*)&vb;
#pragma unroll
    for (int e = 0; e < 8; ++e) {
      unsigned pk2 = (unsigned)pa[e] | ((unsigned)pb[e] << 16);
      *(unsigned*)&Vt[buf][vd0 + e][2 * vkp] = pk2;
    }
  };

  loadKV();        // tile 0
  writeLDS(0);
  loadKV();        // tile 1 (held in regs)
  __syncthreads(); // buf0 visible

  f32x4 ot[4];
#pragma unroll
  for (int f = 0; f < 4; ++f) ot[f] = (f32x4)(0.f);
  float m_run = -1e30f, l_run = 0.f;

  for (int kt = 0; kt < 13; ++kt) {
    const int cur = kt & 1;
    if (kt < 12) {
      writeLDS(cur ^ 1);             // tile kt+1 (safe: readers behind this iter's end barrier)
      if (kt < 11) loadKV();         // tile kt+2; latency spans compute below
    }

    // S^T = K . Q^T
    f32x4 st[4];
#pragma unroll
    for (int f = 0; f < 4; ++f) st[f] = (f32x4)(0.f);
    __builtin_amdgcn_s_setprio(1);
#pragma unroll
    for (int f = 0; f < 4; ++f) {
      bf16x8 ka = *(const bf16x8*)&Ks[cur][f * 16 + c][g * 8];
      st[f] = __builtin_amdgcn_mfma_f32_16x16x32_bf16(ka, qf0, st[f], 0, 0, 0);
    }
#pragma unroll
    for (int f = 0; f < 4; ++f) {
      bf16x8 ka = *(const bf16x8*)&Ks[cur][f * 16 + c][32 + g * 8];
      st[f] = __builtin_amdgcn_mfma_f32_16x16x32_bf16(ka, qf1, st[f], 0, 0, 0);
    }
    __builtin_amdgcn_s_setprio(0);

    if (kt == 12) {                  // mask keys >= 785 (local idx >= 17)
#pragma unroll
      for (int f = 0; f < 4; ++f)
#pragma unroll
        for (int i = 0; i < 4; ++i)
          if (f * 16 + g * 4 + i >= 17) st[f][i] = -1e30f;
    }
    // online softmax (exp2 domain, defer-max THR=8)
    float pmax = -1e30f;
#pragma unroll
    for (int f = 0; f < 4; ++f)
#pragma unroll
      for (int i = 0; i < 4; ++i) pmax = fmaxf(pmax, st[f][i]);
    pmax = fmaxf(pmax, __shfl_xor(pmax, 16));
    pmax = fmaxf(pmax, __shfl_xor(pmax, 32));
    if (!__all(pmax <= m_run + 8.f)) {
      float mnew = fmaxf(m_run, pmax);
      float corr = exp2f(m_run - mnew);
      m_run = mnew;
      l_run *= corr;
#pragma unroll
      for (int f = 0; f < 4; ++f)
#pragma unroll
        for (int i = 0; i < 4; ++i) ot[f][i] *= corr;
    }
    float rs = 0.f;
#pragma unroll
    for (int f = 0; f < 4; ++f) {
      bf16x4 pk;
#pragma unroll
      for (int i = 0; i < 4; ++i) {
        float p = exp2f(st[f][i] - m_run);
        rs += p;
        pk[i] = (__bf16)p;
      }
      *(bf16x4*)&Ps[wid][c][f * 16 + g * 4] = pk;
    }
    rs += __shfl_xor(rs, 16);
    rs += __shfl_xor(rs, 32);
    l_run += rs;

    // O^T += V^T . P^T
    __builtin_amdgcn_s_setprio(1);
#pragma unroll
    for (int s2 = 0; s2 < 2; ++s2) {
      bf16x8 pb2 = *(const bf16x8*)&Ps[wid][c][s2 * 32 + g * 8];
#pragma unroll
      for (int f = 0; f < 4; ++f) {
        bf16x8 va2 = *(const bf16x8*)&Vt[cur][f * 16 + c][s2 * 32 + g * 8];
        ot[f] = __builtin_amdgcn_mfma_f32_16x16x32_bf16(va2, pb2, ot[f], 0, 0, 0);
      }
    }
    __builtin_amdgcn_s_setprio(0);
    __syncthreads();                 // single barrier per tile
  }

  const int t = qt * 64 + wid * 16 + c;
  if (t < T_) {
    float inv = 1.f / l_run;
    __bf16* op = aout + ((size_t)(b * T_ + t)) * Cc + hh * 64;
#pragma unroll
    for (int f = 0; f < 4; ++f) {
      bf16x4 ov;
#pragma unroll
      for (int i = 0; i < 4; ++i) ov[i] = (__bf16)(ot[f][i] * inv);
      *(bf16x4*)(op + f * 16 + g * 4) = ov;
    }
  }
}

// ---------------------------------------------------------------------------
extern "C" void kernel_launch(void* const* d_in, const int* in_sizes, int n_in,
                              void* d_out, int out_size, void* d_ws, size_t ws_size,
                              hipStream_t stream) {
  (void)in_sizes; (void)n_in; (void)out_size; (void)ws_size;
  const float* x        = (const float*)d_in[0];
  const float* conv_w   = (const float*)d_in[1];
  const float* bn_scale = (const float*)d_in[2];
  const float* bn_bias  = (const float*)d_in[3];
  const float* bn_mean  = (const float*)d_in[4];
  const float* bn_var   = (const float*)d_in[5];
  const float* w_qkv    = (const float*)d_in[6];
  const float* w_proj   = (const float*)d_in[7];
  const float* b_proj   = (const float*)d_in[8];

  __bf16* ybf  = (__bf16*)d_ws;            // 3 * BTC
  __bf16* qkvb = ybf + 3 * BTC_;           // 3 * BTC (attn OOB reads spill into aobf: mapped)
  __bf16* aobf = qkvb + 3 * BTC_;          // BTC
  __bf16* wq   = aobf + BTC_;              // 3*192*192
  __bf16* wp   = wq + 3 * Cc * Cc;         // 192*192

  conv3_bn_k<<<dim3(8, B_), 192, 0, stream>>>(
      x, conv_w, bn_scale, bn_bias, bn_mean, bn_var, ybf, w_qkv, w_proj, wq);

  const int mblocks = (BT_ + 127) / 128;   // 197
  gemm_bf16<0><<<dim3(mblocks, 1, 3), 512, 0, stream>>>(ybf, wq, nullptr, qkvb);
  attn_mfma<<<1248, 256, 0, stream>>>(qkvb, aobf);
  gemm_bf16<1><<<dim3(mblocks, 1, 1), 512, 0, stream>>>(aobf, wp, b_proj, d_out);
}

// Round 8
// 176.670 us; speedup vs baseline: 3.1218x; 1.0021x over previous
//
#include <hip/hip_runtime.h>

#define B_   32
#define Hh   28
#define Ww   28
#define Cc   192
#define T_   785
#define BT_  (B_ * T_)          // 25120
#define BTC_ ((size_t)BT_ * Cc) // 4823040
// 192^-0.5 * log2(e): softmax computed in exp2 domain
#define SCALE2 0.10412163388f

typedef __attribute__((ext_vector_type(8))) __bf16 bf16x8;
typedef __attribute__((ext_vector_type(4))) __bf16 bf16x4;
typedef __attribute__((ext_vector_type(4))) float  f32x4;

// ---------------------------------------------------------------------------
// Fused depthwise 3x3 conv + BN (3 branches), 4 output rows per block.
// grid (8, 32), block 192. bx==7 casts w_qkv/w_proj to bf16.
// ---------------------------------------------------------------------------
__global__ __launch_bounds__(192) void conv3_bn_k(
    const float* __restrict__ x, const float* __restrict__ cw,
    const float* __restrict__ g, const float* __restrict__ bb,
    const float* __restrict__ mu, const float* __restrict__ var,
    __bf16* __restrict__ y,
    const float* __restrict__ wqkv, const float* __restrict__ wproj,
    __bf16* __restrict__ wdst)
{
  const int c = threadIdx.x;
  const int bx = blockIdx.x;
  const int b = blockIdx.y;
  if (bx == 7) {                       // weight cast blocks
    int t = b * 192 + c;               // 0..6143
    int base = t * 24;
    const float* src = (base < 3 * Cc * Cc) ? (wqkv + base)
                                            : (wproj + (base - 3 * Cc * Cc));
#pragma unroll
    for (int e = 0; e < 24; e += 4) {
      float4 v = *(const float4*)(src + e);
      wdst[base + e + 0] = (__bf16)v.x;
      wdst[base + e + 1] = (__bf16)v.y;
      wdst[base + e + 2] = (__bf16)v.z;
      wdst[base + e + 3] = (__bf16)v.w;
    }
    return;
  }
  const int h0 = bx * 4;
  float w9[3][9], sc[3], sh[3];
#pragma unroll
  for (int br = 0; br < 3; ++br) {
    sc[br] = g[br * Cc + c] * rsqrtf(var[br * Cc + c] + 1e-5f);
    sh[br] = bb[br * Cc + c] - mu[br * Cc + c] * sc[br];
#pragma unroll
    for (int k = 0; k < 9; ++k) w9[br][k] = cw[(br * Cc + c) * 9 + k];
  }
  const float* xb = x + (size_t)b * T_ * Cc;
  if (bx == 0) {
#pragma unroll
    for (int br = 0; br < 3; ++br)
      y[br * BTC_ + (size_t)b * T_ * Cc + c] = (__bf16)xb[c];   // cls passthrough
  }
  // sliding 3-col window over 6 input rows h0-1 .. h0+4
  float c0[6], c1[6], c2[6];
#pragma unroll
  for (int r = 0; r < 6; ++r) {
    int rr = h0 - 1 + r;
    c0[r] = 0.f;
    c1[r] = (rr >= 0 && rr < Hh) ? xb[(size_t)(1 + rr * Ww) * Cc + c] : 0.f;
  }
  for (int col = 0; col < Ww; ++col) {
#pragma unroll
    for (int r = 0; r < 6; ++r) {
      int rr = h0 - 1 + r, ci = col + 1;
      c2[r] = (rr >= 0 && rr < Hh && ci < Ww)
                ? xb[(size_t)(1 + rr * Ww + ci) * Cc + c] : 0.f;
    }
#pragma unroll
    for (int ro = 0; ro < 4; ++ro) {
      size_t orow = (size_t)(b * T_ + 1 + (h0 + ro) * Ww + col) * Cc + c;
#pragma unroll
      for (int br = 0; br < 3; ++br) {
        float acc = c0[ro+0]*w9[br][0] + c1[ro+0]*w9[br][1] + c2[ro+0]*w9[br][2]
                  + c0[ro+1]*w9[br][3] + c1[ro+1]*w9[br][4] + c2[ro+1]*w9[br][5]
                  + c0[ro+2]*w9[br][6] + c1[ro+2]*w9[br][7] + c2[ro+2]*w9[br][8];
        y[br * BTC_ + orow] = (__bf16)(acc * sc[br] + sh[br]);
      }
    }
#pragma unroll
    for (int r = 0; r < 6; ++r) { c0[r] = c1[r]; c1[r] = c2[r]; }
  }
}

// ---------------------------------------------------------------------------
// MFMA GEMM, full-N tile (128 x 192), A read exactly once. 512 threads,
// 8 waves (2x4), each wave 64x48. K staged in 3 chunks of 64, reg-prefetched.
// No setprio: T5 is null/negative on barrier-lockstep GEMM (m190).
// MODE 0: QKV (blockIdx.z = branch, bf16 out, branch0 * SCALE2).
// MODE 1: proj (f32 out + bias).
// ---------------------------------------------------------------------------
template <int MODE>
__global__ __launch_bounds__(512) void gemm_bf16(
    const __bf16* __restrict__ A0, const __bf16* __restrict__ W0,
    const float* __restrict__ bias, void* __restrict__ outp)
{
  __shared__ __bf16 As[128][72];
  __shared__ __bf16 Bs[192][72];
  const int z = blockIdx.z;
  const __bf16* A  = A0 + (MODE == 0 ? (size_t)z * BTC_ : 0);
  const __bf16* Bw = W0 + (MODE == 0 ? (size_t)z * Cc * Cc : 0);
  const float osc = (MODE == 0 && z == 0) ? SCALE2 : 1.0f;
  const int tid = threadIdx.x;
  const int wid = tid >> 6, l = tid & 63, c = l & 15, g = l >> 4;
  const int wm = wid >> 2, wn = wid & 3;
  const int m0 = blockIdx.x * 128;
  const int ar = tid >> 2, aq = tid & 3;
  const int brow = tid >> 3, bv = tid & 7;

  f32x4 acc[4][3];
#pragma unroll
  for (int i = 0; i < 4; ++i)
#pragma unroll
    for (int j = 0; j < 3; ++j) acc[i][j] = (f32x4)(0.f);

  const __bf16* ap = A + (size_t)(m0 + ar) * Cc + aq * 16;   // OOB rows land in mapped ws; stores guarded
  const __bf16* bp0 = Bw + (size_t)brow * Cc + bv * 8;
  uint4 a0 = *(const uint4*)(ap + 0);
  uint4 a1 = *(const uint4*)(ap + 8);
  uint4 b0 = *(const uint4*)(bp0);
  uint4 b1 = *(const uint4*)(bp0 + (size_t)64 * Cc);
  uint4 b2 = *(const uint4*)(bp0 + (size_t)128 * Cc);

  for (int kc = 0; kc < 3; ++kc) {
    __syncthreads();
    *(uint4*)&As[ar][aq * 16 + 0] = a0;
    *(uint4*)&As[ar][aq * 16 + 8] = a1;
    *(uint4*)&Bs[brow +   0][bv * 8] = b0;
    *(uint4*)&Bs[brow +  64][bv * 8] = b1;
    *(uint4*)&Bs[brow + 128][bv * 8] = b2;
    if (kc < 2) {
      ap += 64; bp0 += 64;
      a0 = *(const uint4*)(ap + 0);
      a1 = *(const uint4*)(ap + 8);
      b0 = *(const uint4*)(bp0);
      b1 = *(const uint4*)(bp0 + (size_t)64 * Cc);
      b2 = *(const uint4*)(bp0 + (size_t)128 * Cc);
    }
    __syncthreads();
#pragma unroll
    for (int ksl = 0; ksl < 2; ++ksl) {
      bf16x8 af[4], bfr[3];
#pragma unroll
      for (int mf = 0; mf < 4; ++mf)
        af[mf] = *(const bf16x8*)&As[wm * 64 + mf * 16 + c][ksl * 32 + g * 8];
#pragma unroll
      for (int nf = 0; nf < 3; ++nf)
        bfr[nf] = *(const bf16x8*)&Bs[wn * 48 + nf * 16 + c][ksl * 32 + g * 8];
#pragma unroll
      for (int mf = 0; mf < 4; ++mf)
#pragma unroll
        for (int nf = 0; nf < 3; ++nf)
          acc[mf][nf] = __builtin_amdgcn_mfma_f32_16x16x32_bf16(
              af[mf], bfr[nf], acc[mf][nf], 0, 0, 0);
    }
  }
  float bias_c[3] = {0.f, 0.f, 0.f};
  if (MODE == 1) {
#pragma unroll
    for (int nf = 0; nf < 3; ++nf) bias_c[nf] = bias[wn * 48 + nf * 16 + c];
  }
#pragma unroll
  for (int mf = 0; mf < 4; ++mf) {
#pragma unroll
    for (int i = 0; i < 4; ++i) {
      int m = m0 + wm * 64 + mf * 16 + g * 4 + i;
      if (m < BT_) {
#pragma unroll
        for (int nf = 0; nf < 3; ++nf) {
          int n = wn * 48 + nf * 16 + c;
          if (MODE == 1)
            ((float*)outp)[(size_t)m * Cc + n] = acc[mf][nf][i] + bias_c[nf];
          else
            ((__bf16*)outp)[z * BTC_ + (size_t)m * Cc + n] =
                (__bf16)(acc[mf][nf][i] * osc);
        }
      }
    }
  }
}

// ---------------------------------------------------------------------------
// MFMA flash attention — r2 structure (single-buffer, 2 barriers/tile,
// no cross-tile reg prefetch: 44-VGPR class, 27.6KB LDS, ~37% occ was the
// measured best) + zero-cost additions: XCD swizzle, exp2-domain softmax
// with defer-max, v_perm transpose pack, setprio on MFMA clusters.
// grid 1248 = 8 XCD chunks x 156. 64 q-rows/block, 4 waves.
// ---------------------------------------------------------------------------
__global__ __launch_bounds__(256) void attn_mfma(
    const __bf16* __restrict__ qkv, __bf16* __restrict__ aout)
{
  __shared__ __bf16 Ks[64][72];      // [key][d]
  __shared__ __bf16 Vt[64][72];      // [d][key]
  __shared__ __bf16 Ps[4][16][72];   // per-wave [qrow][key]
  const int bid = blockIdx.x;
  const int swz = (bid & 7) * 156 + (bid >> 3);
  const int qt = swz % 13;
  const int g2 = swz / 13;
  const int hh = g2 % 3;
  const int b  = g2 / 3;
  const int tid = threadIdx.x;
  const int wid = tid >> 6, l = tid & 63, c = l & 15, g = l >> 4;
  const __bf16* Q = qkv + ((size_t)(0 * B_ + b) * T_) * Cc + hh * 64;
  const __bf16* K = qkv + ((size_t)(1 * B_ + b) * T_) * Cc + hh * 64;
  const __bf16* V = qkv + ((size_t)(2 * B_ + b) * T_) * Cc + hh * 64;

  // Q fragments in registers for all 13 K-tiles (SCALE2 pre-folded).
  // No clamp: OOB rows read adjacent mapped ws data (finite bf16), and
  // their outputs are never stored; masked tail keys give P==0.
  const int qrow = qt * 64 + wid * 16 + c;
  const __bf16* qp = Q + (size_t)qrow * Cc + g * 8;
  bf16x8 qf0 = *(const bf16x8*)(qp);
  bf16x8 qf1 = *(const bf16x8*)(qp + 32);

  const int skey = tid >> 2, sdq = tid & 3;        // K stage ids
  const int vkp = tid & 31, vd0 = (tid >> 5) * 8;  // Vt stage ids
  const __bf16* kp  = K + (size_t)skey * Cc + sdq * 16;
  const __bf16* vp0 = V + (size_t)(2 * vkp + 0) * Cc + vd0;
  const __bf16* vp1 = V + (size_t)(2 * vkp + 1) * Cc + vd0;

  f32x4 ot[4];
#pragma unroll
  for (int f = 0; f < 4; ++f) ot[f] = (f32x4)(0.f);
  float m_run = -1e30f, l_run = 0.f;

  for (int kt = 0; kt < 13; ++kt) {
    __syncthreads();                   // prev tile's LDS reads done
    {
      // stage K rows (row-major) and V transposed (v_perm pack)
      uint4 kr0 = *(const uint4*)(kp + 0);
      uint4 kr1 = *(const uint4*)(kp + 8);
      uint4 va  = *(const uint4*)vp0;
      uint4 vb  = *(const uint4*)vp1;
      kp += 64 * Cc; vp0 += 64 * Cc; vp1 += 64 * Cc;
      *(uint4*)&Ks[skey][sdq * 16 + 0] = kr0;
      *(uint4*)&Ks[skey][sdq * 16 + 8] = kr1;
      const unsigned* aw = (const unsigned*)&va;
      const unsigned* bw = (const unsigned*)&vb;
#pragma unroll
      for (int w = 0; w < 4; ++w) {
        // rows d = vd0+2w (lo halves) and vd0+2w+1 (hi halves)
        unsigned lo = __builtin_amdgcn_perm(bw[w], aw[w], 0x05040100u);
        unsigned hi = __builtin_amdgcn_perm(bw[w], aw[w], 0x07060302u);
        *(unsigned*)&Vt[vd0 + 2 * w + 0][2 * vkp] = lo;
        *(unsigned*)&Vt[vd0 + 2 * w + 1][2 * vkp] = hi;
      }
    }
    __syncthreads();

    // S^T = K . Q^T  (log2-domain scores; SCALE2 folded into Q)
    f32x4 st[4];
#pragma unroll
    for (int f = 0; f < 4; ++f) st[f] = (f32x4)(0.f);
    __builtin_amdgcn_s_setprio(1);
#pragma unroll
    for (int f = 0; f < 4; ++f) {
      bf16x8 ka = *(const bf16x8*)&Ks[f * 16 + c][g * 8];
      st[f] = __builtin_amdgcn_mfma_f32_16x16x32_bf16(ka, qf0, st[f], 0, 0, 0);
    }
#pragma unroll
    for (int f = 0; f < 4; ++f) {
      bf16x8 ka = *(const bf16x8*)&Ks[f * 16 + c][32 + g * 8];
      st[f] = __builtin_amdgcn_mfma_f32_16x16x32_bf16(ka, qf1, st[f], 0, 0, 0);
    }
    __builtin_amdgcn_s_setprio(0);

    if (kt == 12) {                    // mask keys >= 785 (local idx >= 17)
#pragma unroll
      for (int f = 0; f < 4; ++f)
#pragma unroll
        for (int i = 0; i < 4; ++i)
          if (f * 16 + g * 4 + i >= 17) st[f][i] = -1e30f;
    }
    // online softmax (exp2 domain, defer-max THR=8); max3-friendly tree
    float m01 = fmaxf(fmaxf(st[0][0], st[0][1]), fmaxf(st[0][2], st[0][3]));
    float m11 = fmaxf(fmaxf(st[1][0], st[1][1]), fmaxf(st[1][2], st[1][3]));
    float m21 = fmaxf(fmaxf(st[2][0], st[2][1]), fmaxf(st[2][2], st[2][3]));
    float m31 = fmaxf(fmaxf(st[3][0], st[3][1]), fmaxf(st[3][2], st[3][3]));
    float pmax = fmaxf(fmaxf(m01, m11), fmaxf(m21, m31));
    pmax = fmaxf(pmax, __shfl_xor(pmax, 16));
    pmax = fmaxf(pmax, __shfl_xor(pmax, 32));
    if (!__all(pmax <= m_run + 8.f)) {
      float mnew = fmaxf(m_run, pmax);
      float corr = exp2f(m_run - mnew);
      m_run = mnew;
      l_run *= corr;
#pragma unroll
      for (int f = 0; f < 4; ++f)
#pragma unroll
        for (int i = 0; i < 4; ++i) ot[f][i] *= corr;
    }
    float rs = 0.f;
#pragma unroll
    for (int f = 0; f < 4; ++f) {
      bf16x4 pk;
#pragma unroll
      for (int i = 0; i < 4; ++i) {
        float p = exp2f(st[f][i] - m_run);
        rs += p;
        pk[i] = (__bf16)p;
      }
      *(bf16x4*)&Ps[wid][c][f * 16 + g * 4] = pk;
    }
    rs += __shfl_xor(rs, 16);
    rs += __shfl_xor(rs, 32);
    l_run += rs;

    // O^T += V^T . P^T   (Ps written/read by the same wave: lgkm-ordered)
    __builtin_amdgcn_s_setprio(1);
#pragma unroll
    for (int s2 = 0; s2 < 2; ++s2) {
      bf16x8 pb2 = *(const bf16x8*)&Ps[wid][c][s2 * 32 + g * 8];
#pragma unroll
      for (int f = 0; f < 4; ++f) {
        bf16x8 va2 = *(const bf16x8*)&Vt[f * 16 + c][s2 * 32 + g * 8];
        ot[f] = __builtin_amdgcn_mfma_f32_16x16x32_bf16(va2, pb2, ot[f], 0, 0, 0);
      }
    }
    __builtin_amdgcn_s_setprio(0);
  }

  const int t = qt * 64 + wid * 16 + c;
  if (t < T_) {
    float inv = 1.f / l_run;
    __bf16* op = aout + ((size_t)(b * T_ + t)) * Cc + hh * 64;
#pragma unroll
    for (int f = 0; f < 4; ++f) {
      bf16x4 ov;
#pragma unroll
      for (int i = 0; i < 4; ++i) ov[i] = (__bf16)(ot[f][i] * inv);
      *(bf16x4*)(op + f * 16 + g * 4) = ov;
    }
  }
}

// ---------------------------------------------------------------------------
extern "C" void kernel_launch(void* const* d_in, const int* in_sizes, int n_in,
                              void* d_out, int out_size, void* d_ws, size_t ws_size,
                              hipStream_t stream) {
  (void)in_sizes; (void)n_in; (void)out_size; (void)ws_size;
  const float* x        = (const float*)d_in[0];
  const float* conv_w   = (const float*)d_in[1];
  const float* bn_scale = (const float*)d_in[2];
  const float* bn_bias  = (const float*)d_in[3];
  const float* bn_mean  = (const float*)d_in[4];
  const float* bn_var   = (const float*)d_in[5];
  const float* w_qkv    = (const float*)d_in[6];
  const float* w_proj   = (const float*)d_in[7];
  const float* b_proj   = (const float*)d_in[8];

  __bf16* ybf  = (__bf16*)d_ws;            // 3 * BTC
  __bf16* qkvb = ybf + 3 * BTC_;           // 3 * BTC (attn OOB reads spill into aobf: mapped)
  __bf16* aobf = qkvb + 3 * BTC_;          // BTC
  __bf16* wq   = aobf + BTC_;              // 3*192*192
  __bf16* wp   = wq + 3 * Cc * Cc;         // 192*192

  conv3_bn_k<<<dim3(8, B_), 192, 0, stream>>>(
      x, conv_w, bn_scale, bn_bias, bn_mean, bn_var, ybf, w_qkv, w_proj, wq);

  const int mblocks = (BT_ + 127) / 128;   // 197
  gemm_bf16<0><<<dim3(mblocks, 1, 3), 512, 0, stream>>>(ybf, wq, nullptr, qkvb);
  attn_mfma<<<1248, 256, 0, stream>>>(qkvb, aobf);
  gemm_bf16<1><<<dim3(mblocks, 1, 1), 512, 0, stream>>>(aobf, wp, b_proj, d_out);
}